// Round 6
// baseline (198.835 us; speedup 1.0000x reference)
//
#include <hip/hip_runtime.h>
#include <hip/hip_bf16.h>

// SpikingSelfAttention — round 16: i8 k_qkv. Weights split into 4 EXACT i8
// fixed-point planes (w = 2^-7 P0 + 2^-14 P1 + 2^-21 P2 + 2^-28 P3, residual
// <= 2^-36 — more exact than the old 3x bf16 split). Spikes stored as i8.
// mfma_i32_16x16x64_i8 (K=64) -> 2/3 the MFMA of bf16, exact i32 accum.
// B tile (128 l x 512 c i8 = 64KB) resident in LDS, loaded ONCE -> single
// barrier, no per-K-step lockstep (the old 2-barrier ceiling). Planes run as
// 2+2 passes; pair-folds E=(Dhi<<7)+Dlo exact in i32; y = 2^-14 E1 + 2^-28 E2.
// k_kvM (MFMA Gram), k_attn, k_out unchanged from round 15.

#define NB 8
#define NC 512
#define NT 4
#define NN 256
#define NL 1024
#define NH 8
#define ND 64
#define BCL (NB*NC*NL)

typedef __attribute__((ext_vector_type(8))) short  short8v;
typedef __attribute__((ext_vector_type(8))) unsigned short us8;
typedef __attribute__((ext_vector_type(4))) unsigned short us4;
typedef __attribute__((ext_vector_type(4))) float f32x4;
typedef __attribute__((ext_vector_type(4))) int   i32x4;

__device__ __forceinline__ float bu2f(unsigned short u) {
  return __uint_as_float(((unsigned)u) << 16);
}
__device__ __forceinline__ unsigned short f2bu(float f) {   // RNE f32->bf16
  unsigned b = __float_as_uint(f);
  return (unsigned short)((b + 0x7FFFu + ((b >> 16) & 1u)) >> 16);
}

// ---------------------------------------------------------------------------
// k_prep: blocks [0,512) = weight split.
//   p==3 -> 3x bf16 planes into H2 (k_out path, unchanged layout).
//   p<3  -> 4x i8 planes into H8: idx=(p*128 + j*32 + rt*8 + k0), each 8192B
//           block = [qd 4][row 128][16B], fragment = 16 consecutive k-i8.
// blocks [512,1024) = proj BN+LIF -> ST0i[b][l][c] i8 spikes (0/1).
__global__ void k_prep(const float* __restrict__ wq, const float* __restrict__ wk,
                       const float* __restrict__ wv, const float* __restrict__ wp,
                       const float* __restrict__ x,
                       const float* __restrict__ g,  const float* __restrict__ bt,
                       const float* __restrict__ mu, const float* __restrict__ var,
                       unsigned short* __restrict__ H2,
                       signed char* __restrict__ H8,
                       signed char* __restrict__ ST0i) {
  if (blockIdx.x < 512) {
    int gi = blockIdx.x * 256 + threadIdx.x;       // (p,o,k8): 4*512*64
    int p = gi >> 15;
    int o = (gi >> 6) & 511;
    int k8 = gi & 63;
    int rt = o >> 7, r = o & 127;
    int k0i = k8 >> 3, chunk = k8 & 7;
    const float* W = (p == 0) ? wq : (p == 1) ? wk : (p == 2) ? wv : wp;
    const float* src = W + (size_t)o * NC + k8 * 8;
    if (p == 3) {
      us8 a[3];
#pragma unroll
      for (int i = 0; i < 8; i++) {
        float w = src[i];
        unsigned short u1 = f2bu(w);
        float r1 = w - bu2f(u1);
        unsigned short u2 = f2bu(r1);
        float r2 = r1 - bu2f(u2);
        unsigned short u3 = f2bu(r2);
        a[0][i] = u1; a[1][i] = u2; a[2][i] = u3;
      }
#pragma unroll
      for (int j = 0; j < 3; j++) {
        size_t off = ((size_t)((((p * 3 + j) * 4 + rt) * 8 + k0i) * 8 + chunk)) * 1024
                     + (size_t)r * 8;
        *(us8*)&H2[off] = a[j];
      }
    } else {
      unsigned long long pk[4] = {0ull, 0ull, 0ull, 0ull};
#pragma unroll
      for (int i = 0; i < 8; i++) {
        float f = src[i] * 128.0f;
        int P0 = __float2int_rn(f); float rr = f - (float)P0;
        f = rr * 128.0f;
        int P1 = __float2int_rn(f); rr = f - (float)P1;
        f = rr * 128.0f;
        int P2 = __float2int_rn(f); rr = f - (float)P2;
        int P3 = __float2int_rn(rr * 128.0f);
        pk[0] |= (unsigned long long)(unsigned char)(signed char)P0 << (8 * i);
        pk[1] |= (unsigned long long)(unsigned char)(signed char)P1 << (8 * i);
        pk[2] |= (unsigned long long)(unsigned char)(signed char)P2 << (8 * i);
        pk[3] |= (unsigned long long)(unsigned char)(signed char)P3 << (8 * i);
      }
      int qd = (k8 >> 1) & 3, half = k8 & 1;
#pragma unroll
      for (int j = 0; j < 4; j++) {
        size_t addr = ((size_t)(p * 128 + j * 32 + rt * 8 + k0i)) * 8192
                      + (size_t)qd * 2048 + (size_t)r * 16 + half * 8;
        *(unsigned long long*)&H8[addr] = pk[j];
      }
    }
  } else {
    int bidx = blockIdx.x - 512;
    int b  = bidx >> 6;
    int c0 = (bidx & 63) * 8;
    int n  = threadIdx.x;
    unsigned char spk[NT][8];
#pragma unroll
    for (int i = 0; i < 8; i++) {
      int c = c0 + i;
      float inv = g[c] / sqrtf(var[c] + 1e-5f);
      float m = mu[c], be = bt[c];
      const float* xp = x + ((size_t)(b * NC + c)) * NL + n;
      float v = 0.f;
#pragma unroll
      for (int t = 0; t < NT; t++) {
        float y = (xp[t * NN] - m) * inv + be;
        v = v + (y - v) / 1.5f;
        unsigned char s = 0;
        if (v - 1.0f >= 0.f) { s = 1; v = 0.f; }
        spk[t][i] = s;
      }
    }
#pragma unroll
    for (int t = 0; t < NT; t++) {
      unsigned long long pk = 0ull;
#pragma unroll
      for (int i = 0; i < 8; i++) pk |= (unsigned long long)spk[t][i] << (8 * i);
      *(unsigned long long*)&ST0i[((size_t)b * NL + t * NN + n) * NC + c0] = pk;
    }
  }
}

// ---------------------------------------------------------------------------
// Fused q/k/v projection + BN + LIF — i8 MFMA version. 128x128 tile, B tile
// (128 l x 512 c i8 = 64KB) resident in LDS (XOR-swizzled 16B chunks), loaded
// once -> ONE barrier total. 4 i8 planes in 2 passes of 2 (i32 accum pairs,
// exact <<7 fold). Epilogue identical to round 15 (q normal, k/v transposed).
__global__ __launch_bounds__(256) void
k_qkv(const signed char* __restrict__ H8,
      const signed char* __restrict__ ST0i,
      const float* __restrict__ gq, const float* __restrict__ bq,
      const float* __restrict__ mq, const float* __restrict__ vq,
      const float* __restrict__ gk, const float* __restrict__ bk,
      const float* __restrict__ mk, const float* __restrict__ vk,
      const float* __restrict__ gv, const float* __restrict__ bv,
      const float* __restrict__ mv, const float* __restrict__ vv,
      unsigned short* __restrict__ STq, unsigned short* __restrict__ STkT,
      unsigned short* __restrict__ STvT) {
  __shared__ __align__(16) signed char sBi[128 * 512];   // 64 KB

  int id = blockIdx.x;                  // 768 = 8 xcd * 96 slot
  int xcd = id & 7, slot = id >> 3;
  int qq = xcd * 96 + slot;             // ordered by (p, rt, b, n0)
  int grp = qq >> 6, mi = qq & 63;      // grp = p*4+rt in [0,12)
  int p = grp >> 2, rt = grp & 3;
  int b = mi >> 3;
  int n0 = (mi & 7) * 32;

  int tid = threadIdx.x;
  int w = tid >> 6, lane = tid & 63, quad = lane >> 4, l15 = lane & 15;
  int xorv = l15 & 7;

  // ---- stage full B tile (once) ----
  const signed char* Sb = ST0i + (size_t)b * NL * NC;
#pragma unroll
  for (int i = 0; i < 16; i++) {
    int gidx = tid + i * 256;
    int cc = gidx >> 5, ph = gidx & 31;
    int t = (cc >> 4) & 3, nn = (cc & 15) | ((cc >> 6) << 4);
    i32x4 v = *(const i32x4*)&Sb[(size_t)(t * NN + n0 + nn) * NC + ph * 16];
    int php = (ph & 24) | ((ph & 7) ^ (cc & 7));
    *(i32x4*)&sBi[cc * 512 + php * 16] = v;
  }
  __syncthreads();

  const signed char* Hb = H8 + ((size_t)(p * 128 + rt * 8)) * 8192;

  i32x4 accA[2][8], accB[2][8], E1[2][8];

#define QPASS(JA, JB)                                                        \
  _Pragma("unroll") for (int ri = 0; ri < 2; ri++)                           \
    _Pragma("unroll") for (int jj = 0; jj < 8; jj++) {                       \
      accA[ri][jj] = (i32x4){0, 0, 0, 0};                                    \
      accB[ri][jj] = (i32x4){0, 0, 0, 0};                                    \
    }                                                                        \
  _Pragma("unroll") for (int k0 = 0; k0 < 8; k0++) {                         \
    const signed char* HA = Hb + ((size_t)((JA) * 32 + k0)) * 8192           \
                            + (size_t)quad * 2048;                           \
    const signed char* HB = Hb + ((size_t)((JB) * 32 + k0)) * 8192           \
                            + (size_t)quad * 2048;                           \
    i32x4 a00 = *(const i32x4*)&HA[(w * 32 + l15) * 16];                     \
    i32x4 a01 = *(const i32x4*)&HA[(w * 32 + 16 + l15) * 16];                \
    i32x4 a10 = *(const i32x4*)&HB[(w * 32 + l15) * 16];                     \
    i32x4 a11 = *(const i32x4*)&HB[(w * 32 + 16 + l15) * 16];                \
    int ph = k0 * 4 + quad;                                                  \
    int php = (ph & 24) | ((ph & 7) ^ xorv);                                 \
    __builtin_amdgcn_s_setprio(1);                                           \
    _Pragma("unroll") for (int jj = 0; jj < 8; jj++) {                       \
      i32x4 bv = *(const i32x4*)&sBi[(jj * 16 + l15) * 512 + php * 16];      \
      accA[0][jj] = __builtin_amdgcn_mfma_i32_16x16x64_i8(                   \
          a00, bv, accA[0][jj], 0, 0, 0);                                    \
      accA[1][jj] = __builtin_amdgcn_mfma_i32_16x16x64_i8(                   \
          a01, bv, accA[1][jj], 0, 0, 0);                                    \
      accB[0][jj] = __builtin_amdgcn_mfma_i32_16x16x64_i8(                   \
          a10, bv, accB[0][jj], 0, 0, 0);                                    \
      accB[1][jj] = __builtin_amdgcn_mfma_i32_16x16x64_i8(                   \
          a11, bv, accB[1][jj], 0, 0, 0);                                    \
    }                                                                        \
    __builtin_amdgcn_s_setprio(0);                                           \
  }

  QPASS(0, 1)
#pragma unroll
  for (int ri = 0; ri < 2; ri++)
#pragma unroll
    for (int jj = 0; jj < 8; jj++)
      E1[ri][jj] = (accA[ri][jj] << 7) + accB[ri][jj];

  QPASS(2, 3)
#pragma unroll
  for (int ri = 0; ri < 2; ri++)
#pragma unroll
    for (int jj = 0; jj < 8; jj++)
      accA[ri][jj] = (accA[ri][jj] << 7) + accB[ri][jj];   // E2 in accA

#undef QPASS

  const float S1 = 0x1p-14f, S2 = 0x1p-28f;
  const float *g, *bb, *mpt, *vr;
  unsigned short* So;
  if (p == 0)      { g = gq; bb = bq; mpt = mq; vr = vq; So = STq; }
  else if (p == 1) { g = gk; bb = bk; mpt = mk; vr = vk; So = STkT; }
  else             { g = gv; bb = bv; mpt = mv; vr = vv; So = STvT; }
  So += (size_t)b * NL * NC;

#pragma unroll
  for (int ri = 0; ri < 2; ri++) {
    int ob = rt * 128 + w * 32 + ri * 16 + quad * 4;
    float av[4], mvv[4], bvv[4];
#pragma unroll
    for (int r = 0; r < 4; r++) {
      av[r]  = g[ob + r] / sqrtf(vr[ob + r] + 1e-5f);
      mvv[r] = mpt[ob + r];
      bvv[r] = bb[ob + r];
    }
#pragma unroll
    for (int nh = 0; nh < 2; nh++) {
      int n = n0 + (nh << 4) + l15;
      unsigned short sp[4][4];          // [t][r]
#pragma unroll
      for (int r = 0; r < 4; r++) {
        float vmem = 0.f;
#pragma unroll
        for (int t = 0; t < NT; t++) {
          int jj = nh * 4 + t;
          float y0 = (float)E1[ri][jj][r] * S1 + (float)accA[ri][jj][r] * S2;
          float y = (y0 - mvv[r]) * av[r] + bvv[r];
          vmem = vmem + (y - vmem) / 1.5f;
          unsigned short s = 0;
          if (vmem - 1.0f >= 0.f) { s = 0x3F80; vmem = 0.f; }
          sp[t][r] = s;
        }
      }
      if (p == 0) {
#pragma unroll
        for (int t = 0; t < NT; t++) {
          us4 pk;
#pragma unroll
          for (int r = 0; r < 4; r++) pk[r] = sp[t][r];
          *(us4*)&So[(size_t)(t * NN + n) * NC + ob] = pk;
        }
      } else {
        // transposed [c][l]: c = ob+r, l = t*NN+n
#pragma unroll
        for (int t = 0; t < NT; t++)
#pragma unroll
          for (int r = 0; r < 4; r++)
            So[(size_t)(ob + r) * NL + t * NN + n] = sp[t][r];
      }
    }
  }
}

// ---------------------------------------------------------------------------
// MFMA Gram: Mpart[ch][bh][e][dd] = sum_{l in 128-chunk} K[l][e]*V[l][dd].
// KT/VT are [c][l] -> both fragments are contiguous us8 loads; LDS-free.
__global__ __launch_bounds__(256) void
k_kvM(const unsigned short* __restrict__ STkT,
      const unsigned short* __restrict__ STvT,
      float* __restrict__ Mpart) {
  int bh = blockIdx.x, ch = blockIdx.y;       // ch 0..7
  int b = bh >> 3, h = bh & 7;
  const unsigned short* KT = STkT + ((size_t)(b * NC + h * ND)) * NL;
  const unsigned short* VT = STvT + ((size_t)(b * NC + h * ND)) * NL;
  int tid = threadIdx.x;
  int w = tid >> 6, lane = tid & 63, quad = lane >> 4, l15 = lane & 15;
  int lb = ch * 128;

  f32x4 acc[4];
#pragma unroll
  for (int jj = 0; jj < 4; jj++) acc[jj] = (f32x4){0.f, 0.f, 0.f, 0.f};

#pragma unroll
  for (int ks = 0; ks < 4; ks++) {
    int lc = lb + ks * 32 + quad * 8;
    short8v a = *(const short8v*)&KT[(size_t)(w * 16 + l15) * NL + lc];
#pragma unroll
    for (int jj = 0; jj < 4; jj++) {
      short8v bv = *(const short8v*)&VT[(size_t)(jj * 16 + l15) * NL + lc];
      acc[jj] = __builtin_amdgcn_mfma_f32_16x16x32_bf16(a, bv, acc[jj], 0, 0, 0);
    }
  }

  float* Mp = Mpart + ((size_t)ch * 64 + bh) * 4096;
#pragma unroll
  for (int jj = 0; jj < 4; jj++)
#pragma unroll
    for (int r = 0; r < 4; r++)
      Mp[(w * 16 + quad * 4 + r) * ND + jj * 16 + l15] = acc[jj][r];
}

// ---------------------------------------------------------------------------
// MFMA attention: O^T[dd][l] = sum_e (M1+M2)^T[dd][e] * Q[l][e]; spike O>=12.
__global__ __launch_bounds__(256) void
k_attn(const unsigned short* __restrict__ STq,
       const float* __restrict__ Mpart,
       unsigned short* __restrict__ STs) {
  __shared__ unsigned short MT1[64 * 64];   // [dd][e], 16B chunks phys = c ^ (dd&7)
  __shared__ unsigned short MT2[64 * 64];
  int lt = blockIdx.x, bh = blockIdx.y;
  int b = bh >> 3, h = bh & 7;
  int tid = threadIdx.x;
  int w = tid >> 6, lane = tid & 63, quad = lane >> 4, l15 = lane & 15;

#pragma unroll
  for (int i = 0; i < 4; i++) {
    int idx4 = tid + i * 256;
    float4 s = ((const float4*)Mpart)[(size_t)bh * 1024 + idx4];
#pragma unroll
    for (int ch = 1; ch < 8; ch++) {
      float4 t = ((const float4*)Mpart)[((size_t)ch * 64 + bh) * 1024 + idx4];
      s.x += t.x; s.y += t.y; s.z += t.z; s.w += t.w;
    }
    int e = idx4 >> 4;
    int dd0 = (idx4 * 4) & 63;
    int chunk = e >> 3;
    float sv[4] = {s.x, s.y, s.z, s.w};
#pragma unroll
    for (int r = 0; r < 4; r++) {
      int dd = dd0 + r;
      unsigned short u1 = f2bu(sv[r]);
      unsigned short u2 = f2bu(sv[r] - bu2f(u1));
      int pos = dd * 64 + (((chunk ^ (dd & 7)) << 3) | (e & 7));
      MT1[pos] = u1;
      MT2[pos] = u2;
    }
  }
  __syncthreads();

  const unsigned short* Qp = STq + (size_t)b * NL * NC + h * ND;
  int lbase = lt * 256 + w * 64;

  f32x4 acc[4][4];                           // [ddtile][ltile]
#pragma unroll
  for (int dt = 0; dt < 4; dt++)
#pragma unroll
    for (int j = 0; j < 4; j++) acc[dt][j] = (f32x4){0.f, 0.f, 0.f, 0.f};

#pragma unroll
  for (int ks = 0; ks < 2; ks++) {
    short8v bq[4];
#pragma unroll
    for (int ltile = 0; ltile < 4; ltile++)
      bq[ltile] = *(const short8v*)&Qp[(size_t)(lbase + ltile * 16 + l15) * NC
                                       + ks * 32 + quad * 8];
    int c8 = ks * 4 + quad;
#pragma unroll
    for (int dt = 0; dt < 4; dt++) {
      int dd = dt * 16 + l15;
      int off = dd * 64 + ((c8 ^ (dd & 7)) << 3);
      short8v a1 = *(const short8v*)&MT1[off];
      short8v a2 = *(const short8v*)&MT2[off];
#pragma unroll
      for (int ltile = 0; ltile < 4; ltile++) {
        acc[dt][ltile] = __builtin_amdgcn_mfma_f32_16x16x32_bf16(a1, bq[ltile], acc[dt][ltile], 0, 0, 0);
        acc[dt][ltile] = __builtin_amdgcn_mfma_f32_16x16x32_bf16(a2, bq[ltile], acc[dt][ltile], 0, 0, 0);
      }
    }
  }

  unsigned short* Sp = STs + (size_t)b * NL * NC + h * ND;
#pragma unroll
  for (int dt = 0; dt < 4; dt++)
#pragma unroll
    for (int ltile = 0; ltile < 4; ltile++) {
      int l = lbase + ltile * 16 + l15;
      int dd = dt * 16 + quad * 4;
      us4 pk;
#pragma unroll
      for (int r = 0; r < 4; r++) pk[r] = (acc[dt][ltile][r] >= 12.0f) ? 0x3F80 : 0;
      *(us4*)&Sp[(size_t)l * NC + dd] = pk;
    }
}

// ---------------------------------------------------------------------------
// Final projection: 16x16x32 bf16, 128 rows x 64 cols; XCD-grouped swizzle +
// A-register double-buffer (round-11/15 version, unchanged).
__global__ __launch_bounds__(256) void
k_out(const unsigned short* __restrict__ H2,
      const unsigned short* __restrict__ STs,
      const float* __restrict__ bp, float* __restrict__ out) {
  __shared__ __align__(16) unsigned short sB[2][64 * 64];

  int id = blockIdx.x;                  // 512 = 8 xcd * 64 slot
  int xcd = id & 7, slot = id >> 3;
  int qq = xcd * 64 + slot;             // ordered by (rt, b, l0)
  int rt = qq >> 7;
  int mi = qq & 127;
  int b  = mi >> 4;
  int l0 = (mi & 15) * 64;

  int tid = threadIdx.x;
  int w = tid >> 6, lane = tid & 63, quad = lane >> 4, l15 = lane & 15;
  int xorv = l15 & 7;

  const unsigned short* Sb = STs + (size_t)b * NL * NC;
  const unsigned short* Hbase = H2 + ((size_t)(9 * 4 + rt) * 8) * 8192;  // p=3

  f32x4 acc[2][4];
#pragma unroll
  for (int ri = 0; ri < 2; ri++)
#pragma unroll
    for (int jj = 0; jj < 4; jj++) acc[ri][jj] = (f32x4){0.f, 0.f, 0.f, 0.f};

  short8v A0[2][3][2], A1[2][3][2];

#define OLOADA(DST, K0I)                                                     \
  _Pragma("unroll") for (int ks = 0; ks < 2; ks++) {                         \
    int c8 = ks * 4 + quad;                                                  \
    _Pragma("unroll") for (int j = 0; j < 3; j++) {                          \
      const unsigned short* Hj =                                             \
          Hbase + ((size_t)(j * 4 * 8 + (K0I))) * 8192 + (size_t)c8 * 1024;  \
      DST[ks][j][0] = *(const short8v*)&Hj[(w * 32 + l15) * 8];              \
      DST[ks][j][1] = *(const short8v*)&Hj[(w * 32 + 16 + l15) * 8];         \
    }                                                                        \
  }

  OLOADA(A0, 0);

  us8 breg[2];
  int ccs[2], segs[2];
  size_t bsrc[2];
#pragma unroll
  for (int i = 0; i < 2; i++) {
    int idx = tid + i * 256;
    int cc = idx >> 3, seg = idx & 7;
    ccs[i] = cc; segs[i] = seg;
    bsrc[i] = (size_t)(l0 + cc) * NC + seg * 8;
  }
#pragma unroll
  for (int i = 0; i < 2; i++) breg[i] = *(const us8*)&Sb[bsrc[i]];
#pragma unroll
  for (int i = 0; i < 2; i++)
    *(us8*)&sB[0][ccs[i] * 64 + ((segs[i] ^ (ccs[i] & 7)) << 3)] = breg[i];

#define OBPRE(K0N)                                                           \
  _Pragma("unroll") for (int i = 0; i < 2; i++)                              \
    breg[i] = *(const us8*)&Sb[bsrc[i] + (size_t)(K0N) * 64];

#define OBWRITE(BUFN)                                                        \
  _Pragma("unroll") for (int i = 0; i < 2; i++)                              \
    *(us8*)&sB[BUFN][ccs[i] * 64 + ((segs[i] ^ (ccs[i] & 7)) << 3)] = breg[i];

#define OMFMAS(AR, BUF)                                                      \
  _Pragma("unroll") for (int ks = 0; ks < 2; ks++) {                         \
    int c8 = ks * 4 + quad;                                                  \
    int poff = (c8 ^ xorv) << 3;                                             \
    short8v bf[4];                                                           \
    _Pragma("unroll") for (int jj = 0; jj < 4; jj++)                         \
      bf[jj] = *(const short8v*)&sB[BUF][(jj * 16 + l15) * 64 + poff];       \
    _Pragma("unroll") for (int j = 0; j < 3; j++)                            \
      _Pragma("unroll") for (int jj = 0; jj < 4; jj++) {                     \
        acc[0][jj] = __builtin_amdgcn_mfma_f32_16x16x32_bf16(                \
            AR[ks][j][0], bf[jj], acc[0][jj], 0, 0, 0);                      \
        acc[1][jj] = __builtin_amdgcn_mfma_f32_16x16x32_bf16(                \
            AR[ks][j][1], bf[jj], acc[1][jj], 0, 0, 0);                      \
      }                                                                      \
  }

#define OSTEP(K0I, ACUR, ANXT)                                               \
  __syncthreads();                                                           \
  { if ((K0I) < 7) { OLOADA(ANXT, (K0I) + 1); } }                            \
  { if ((K0I) < 7) { OBPRE((K0I) + 1); } }                                   \
  OMFMAS(ACUR, (K0I) & 1);                                                   \
  { if ((K0I) < 7) { OBWRITE(((K0I) & 1) ^ 1); } }

  OSTEP(0, A0, A1)
  OSTEP(1, A1, A0)
  OSTEP(2, A0, A1)
  OSTEP(3, A1, A0)
  OSTEP(4, A0, A1)
  OSTEP(5, A1, A0)
  OSTEP(6, A0, A1)
  OSTEP(7, A1, A0)

#undef OLOADA
#undef OBPRE
#undef OBWRITE
#undef OMFMAS
#undef OSTEP

#pragma unroll
  for (int ri = 0; ri < 2; ri++) {
    int ob = rt * 128 + w * 32 + ri * 16 + quad * 4;
#pragma unroll
    for (int jj = 0; jj < 4; jj++) {
      int l = l0 + jj * 16 + l15;
#pragma unroll
      for (int r = 0; r < 4; r++)
        out[((size_t)(b * NC + ob + r)) * NL + l] = acc[ri][jj][r] + bp[ob + r];
    }
  }
}

// ---------------------------------------------------------------------------
extern "C" void kernel_launch(void* const* d_in, const int* in_sizes, int n_in,
                              void* d_out, int out_size, void* d_ws, size_t ws_size,
                              hipStream_t stream) {
  (void)in_sizes; (void)n_in; (void)out_size; (void)ws_size;
  const float* x   = (const float*)d_in[0];
  const float* wq  = (const float*)d_in[1];
  const float* wk  = (const float*)d_in[2];
  const float* wv  = (const float*)d_in[3];
  const float* wp  = (const float*)d_in[4];
  const float* bp  = (const float*)d_in[5];
  const float* gq  = (const float*)d_in[6];
  const float* bq  = (const float*)d_in[7];
  const float* mq  = (const float*)d_in[8];
  const float* vq  = (const float*)d_in[9];
  const float* gk  = (const float*)d_in[10];
  const float* bk  = (const float*)d_in[11];
  const float* mk  = (const float*)d_in[12];
  const float* vk  = (const float*)d_in[13];
  const float* gv  = (const float*)d_in[14];
  const float* bv  = (const float*)d_in[15];
  const float* mv  = (const float*)d_in[16];
  const float* vvv = (const float*)d_in[17];
  const float* gp  = (const float*)d_in[18];
  const float* bpn = (const float*)d_in[19];
  const float* mp  = (const float*)d_in[20];
  const float* vp  = (const float*)d_in[21];

  unsigned short* H2 = (unsigned short*)d_ws;              // 4*3*NC*NC shorts (p=3 used)
  signed char* H8    = (signed char*)(H2 + (size_t)4 * 3 * NC * NC);  // 4*4*NC*NC bytes
  signed char* ST0i  = H8 + (size_t)4 * 4 * NC * NC;       // BCL bytes
  unsigned short* STq  = (unsigned short*)(ST0i + (size_t)BCL);
  unsigned short* STkT = STq + BCL;
  unsigned short* STvT = STkT + BCL;
  unsigned short* STs  = STvT + BCL;
  float* Mpart = (float*)(STs + BCL);

  dim3 blk(256);
  k_prep<<<1024, blk, 0, stream>>>(wq, wk, wv, wp, x, gp, bpn, mp, vp, H2, H8, ST0i);
  k_qkv<<<768, blk, 0, stream>>>(H8, ST0i,
      gq, bq, mq, vq, gk, bk, mk, vk, gv, bv, mv, vvv, STq, STkT, STvT);
  k_kvM<<<dim3(64, 8), blk, 0, stream>>>(STkT, STvT, Mpart);
  k_attn<<<dim3(4, 64), blk, 0, stream>>>(STq, Mpart, STs);
  k_out<<<512, blk, 0, stream>>>(H2, STs, bp, (float*)d_out);
}

// Round 7
// 197.380 us; speedup vs baseline: 1.0074x; 1.0074x over previous
//
#include <hip/hip_runtime.h>
#include <hip/hip_bf16.h>

// SpikingSelfAttention — round 17: revert k_prep/k_qkv/k_out to round 15
// (184.9us best; i8 k_qkv regressed on occupancy+bank-conflicts). Change:
// k_kvM computes the FULL-K Gram in one pass (grid 64, 32 K-slices/wave) ->
// Mpart is 64x4096 floats (1MB, was 8MB); k_attn prologue is a single 16KB
// read, no 8-way reduce. Gram sums are integers (0/1 spikes) -> fp32-exact,
// order-free -> bit-identical numerics.

#define NB 8
#define NC 512
#define NT 4
#define NN 256
#define NL 1024
#define NH 8
#define ND 64
#define BCL (NB*NC*NL)

typedef __attribute__((ext_vector_type(8))) short  short8v;
typedef __attribute__((ext_vector_type(8))) unsigned short us8;
typedef __attribute__((ext_vector_type(4))) unsigned short us4;
typedef __attribute__((ext_vector_type(4))) float f32x4;

__device__ __forceinline__ float bu2f(unsigned short u) {
  return __uint_as_float(((unsigned)u) << 16);
}
__device__ __forceinline__ unsigned short f2bu(float f) {   // RNE f32->bf16
  unsigned b = __float_as_uint(f);
  return (unsigned short)((b + 0x7FFFu + ((b >> 16) & 1u)) >> 16);
}

// ---------------------------------------------------------------------------
// k_prep: blocks [0,512) = weight split into fragment-ordered H2;
//         blocks [512,1024) = proj BN+LIF -> ST0[b][l][c] bf16.
// H2 layout: offset = ((((p*3+j)*4+rt)*8+k0i)*8+chunk)*1024 + r*8
__global__ void k_prep(const float* __restrict__ wq, const float* __restrict__ wk,
                       const float* __restrict__ wv, const float* __restrict__ wp,
                       const float* __restrict__ x,
                       const float* __restrict__ g,  const float* __restrict__ bt,
                       const float* __restrict__ mu, const float* __restrict__ var,
                       unsigned short* __restrict__ H2,
                       unsigned short* __restrict__ ST0) {
  if (blockIdx.x < 512) {
    int gi = blockIdx.x * 256 + threadIdx.x;       // (p,o,k8): 4*512*64
    int p = gi >> 15;
    int o = (gi >> 6) & 511;
    int k8 = gi & 63;
    int rt = o >> 7, r = o & 127;
    int k0i = k8 >> 3, chunk = k8 & 7;
    const float* W = (p == 0) ? wq : (p == 1) ? wk : (p == 2) ? wv : wp;
    const float* src = W + (size_t)o * NC + k8 * 8;
    us8 a[3];
#pragma unroll
    for (int i = 0; i < 8; i++) {
      float w = src[i];
      unsigned short u1 = f2bu(w);
      float r1 = w - bu2f(u1);
      unsigned short u2 = f2bu(r1);
      float r2 = r1 - bu2f(u2);
      unsigned short u3 = f2bu(r2);
      a[0][i] = u1; a[1][i] = u2; a[2][i] = u3;
    }
#pragma unroll
    for (int j = 0; j < 3; j++) {
      size_t off = ((size_t)((((p * 3 + j) * 4 + rt) * 8 + k0i) * 8 + chunk)) * 1024
                   + (size_t)r * 8;
      *(us8*)&H2[off] = a[j];
    }
  } else {
    int bidx = blockIdx.x - 512;
    int b  = bidx >> 6;
    int c0 = (bidx & 63) * 8;
    int n  = threadIdx.x;
    unsigned short spk[NT][8];
#pragma unroll
    for (int i = 0; i < 8; i++) {
      int c = c0 + i;
      float inv = g[c] / sqrtf(var[c] + 1e-5f);
      float m = mu[c], be = bt[c];
      const float* xp = x + ((size_t)(b * NC + c)) * NL + n;
      float v = 0.f;
#pragma unroll
      for (int t = 0; t < NT; t++) {
        float y = (xp[t * NN] - m) * inv + be;
        v = v + (y - v) / 1.5f;
        unsigned short s = 0;
        if (v - 1.0f >= 0.f) { s = 0x3F80; v = 0.f; }
        spk[t][i] = s;
      }
    }
#pragma unroll
    for (int t = 0; t < NT; t++) {
      us8 pk;
#pragma unroll
      for (int i = 0; i < 8; i++) pk[i] = spk[t][i];
      *(us8*)&ST0[((size_t)b * NL + t * NN + n) * NC + c0] = pk;
    }
  }
}

// ---------------------------------------------------------------------------
// Fused q/k/v projection + BN + LIF. 16x16x32 MFMA, 128x128 tile, 4x1 wave
// strips. XCD-grouped swizzle + A-register double-buffer (round-11 core).
// Epilogue: q written normal [l][c] (STq); k,v written TRANSPOSED [c][l].
__global__ __launch_bounds__(256) void
k_qkv(const unsigned short* __restrict__ H2,
      const unsigned short* __restrict__ ST0,
      const float* __restrict__ gq, const float* __restrict__ bq,
      const float* __restrict__ mq, const float* __restrict__ vq,
      const float* __restrict__ gk, const float* __restrict__ bk,
      const float* __restrict__ mk, const float* __restrict__ vk,
      const float* __restrict__ gv, const float* __restrict__ bv,
      const float* __restrict__ mv, const float* __restrict__ vv,
      unsigned short* __restrict__ STq, unsigned short* __restrict__ STkT,
      unsigned short* __restrict__ STvT) {
  __shared__ __align__(16) unsigned short sB[2][128 * 64];

  int id = blockIdx.x;                  // 768 = 8 xcd * 96 slot
  int xcd = id & 7, slot = id >> 3;
  int qq = xcd * 96 + slot;             // ordered by (p, rt, b, n0)
  int grp = qq >> 6, mi = qq & 63;      // grp = p*4+rt in [0,12)
  int p = grp >> 2, rt = grp & 3;
  int b = mi >> 3;
  int n0 = (mi & 7) * 32;

  int tid = threadIdx.x;
  int w = tid >> 6, lane = tid & 63, quad = lane >> 4, l15 = lane & 15;
  int xorv = l15 & 7;

  const unsigned short* Sb = ST0 + (size_t)b * NL * NC;
  const unsigned short* Hbase = H2 + ((size_t)((p * 3) * 4 + rt) * 8) * 8192;

  f32x4 acc[2][8];
#pragma unroll
  for (int ri = 0; ri < 2; ri++)
#pragma unroll
    for (int jj = 0; jj < 8; jj++) acc[ri][jj] = (f32x4){0.f, 0.f, 0.f, 0.f};

  // A-fragment double-buffer register sets (named, compile-time indexed).
  short8v A0[2][3][2], A1[2][3][2];

#define QLOADA(DST, K0I)                                                     \
  _Pragma("unroll") for (int ks = 0; ks < 2; ks++) {                         \
    int c8 = ks * 4 + quad;                                                  \
    _Pragma("unroll") for (int j = 0; j < 3; j++) {                          \
      const unsigned short* Hj =                                             \
          Hbase + ((size_t)(j * 4 * 8 + (K0I))) * 8192 + (size_t)c8 * 1024;  \
      DST[ks][j][0] = *(const short8v*)&Hj[(w * 32 + l15) * 8];              \
      DST[ks][j][1] = *(const short8v*)&Hj[(w * 32 + 16 + l15) * 8];         \
    }                                                                        \
  }

  QLOADA(A0, 0);                        // prologue A; latency hides under B-stage

  us8 breg[4];
  int ccs[4], segs[4];
  size_t bsrc[4];
#pragma unroll
  for (int i = 0; i < 4; i++) {
    int idx = tid + i * 256;
    int cc = idx >> 3, seg = idx & 7;
    int t = (cc >> 4) & 3, nn = (cc & 15) | ((cc >> 6) << 4);
    ccs[i] = cc; segs[i] = seg;
    bsrc[i] = (size_t)(t * NN + n0 + nn) * NC + seg * 8;
  }
#pragma unroll
  for (int i = 0; i < 4; i++) breg[i] = *(const us8*)&Sb[bsrc[i]];      // k0=0
#pragma unroll
  for (int i = 0; i < 4; i++)
    *(us8*)&sB[0][ccs[i] * 64 + ((segs[i] ^ (ccs[i] & 7)) << 3)] = breg[i];

#define QBPRE(K0N)                                                           \
  _Pragma("unroll") for (int i = 0; i < 4; i++)                              \
    breg[i] = *(const us8*)&Sb[bsrc[i] + (size_t)(K0N) * 64];

#define QBWRITE(BUFN)                                                        \
  _Pragma("unroll") for (int i = 0; i < 4; i++)                              \
    *(us8*)&sB[BUFN][ccs[i] * 64 + ((segs[i] ^ (ccs[i] & 7)) << 3)] = breg[i];

#define QMFMAS(AR, BUF)                                                      \
  _Pragma("unroll") for (int ks = 0; ks < 2; ks++) {                         \
    int c8 = ks * 4 + quad;                                                  \
    int poff = (c8 ^ xorv) << 3;                                             \
    short8v bf[8];                                                           \
    _Pragma("unroll") for (int jj = 0; jj < 8; jj++)                         \
      bf[jj] = *(const short8v*)&sB[BUF][(jj * 16 + l15) * 64 + poff];       \
    _Pragma("unroll") for (int j = 0; j < 3; j++)                            \
      _Pragma("unroll") for (int jj = 0; jj < 8; jj++) {                     \
        acc[0][jj] = __builtin_amdgcn_mfma_f32_16x16x32_bf16(                \
            AR[ks][j][0], bf[jj], acc[0][jj], 0, 0, 0);                      \
        acc[1][jj] = __builtin_amdgcn_mfma_f32_16x16x32_bf16(                \
            AR[ks][j][1], bf[jj], acc[1][jj], 0, 0, 0);                      \
      }                                                                      \
  }

  // Per step: barrier -> issue NEXT A + NEXT B loads -> MFMA on current A
  // (hides next-A latency under current MFMA burst) -> stage next B to LDS.
#define QSTEP(K0I, ACUR, ANXT)                                               \
  __syncthreads();                                                           \
  { if ((K0I) < 7) { QLOADA(ANXT, (K0I) + 1); } }                            \
  { if ((K0I) < 7) { QBPRE((K0I) + 1); } }                                   \
  QMFMAS(ACUR, (K0I) & 1);                                                   \
  { if ((K0I) < 7) { QBWRITE(((K0I) & 1) ^ 1); } }

  QSTEP(0, A0, A1)
  QSTEP(1, A1, A0)
  QSTEP(2, A0, A1)
  QSTEP(3, A1, A0)
  QSTEP(4, A0, A1)
  QSTEP(5, A1, A0)
  QSTEP(6, A0, A1)
  QSTEP(7, A1, A0)

#undef QLOADA
#undef QBPRE
#undef QBWRITE
#undef QMFMAS
#undef QSTEP

  const float *g, *bb, *mpt, *vr;
  unsigned short* So;
  if (p == 0)      { g = gq; bb = bq; mpt = mq; vr = vq; So = STq; }
  else if (p == 1) { g = gk; bb = bk; mpt = mk; vr = vk; So = STkT; }
  else             { g = gv; bb = bv; mpt = mv; vr = vv; So = STvT; }
  So += (size_t)b * NL * NC;            // same byte offset for both layouts

#pragma unroll
  for (int ri = 0; ri < 2; ri++) {
    int ob = rt * 128 + w * 32 + ri * 16 + quad * 4;
    float av[4], mvv[4], bvv[4];
#pragma unroll
    for (int r = 0; r < 4; r++) {
      av[r]  = g[ob + r] / sqrtf(vr[ob + r] + 1e-5f);
      mvv[r] = mpt[ob + r];
      bvv[r] = bb[ob + r];
    }
#pragma unroll
    for (int nh = 0; nh < 2; nh++) {
      int n = n0 + (nh << 4) + l15;
      unsigned short sp[4][4];          // [t][r]
#pragma unroll
      for (int r = 0; r < 4; r++) {
        float vmem = 0.f;
#pragma unroll
        for (int t = 0; t < NT; t++) {
          float y = (acc[ri][nh * 4 + t][r] - mvv[r]) * av[r] + bvv[r];
          vmem = vmem + (y - vmem) / 1.5f;
          unsigned short s = 0;
          if (vmem - 1.0f >= 0.f) { s = 0x3F80; vmem = 0.f; }
          sp[t][r] = s;
        }
      }
      if (p == 0) {
#pragma unroll
        for (int t = 0; t < NT; t++) {
          us4 pk;
#pragma unroll
          for (int r = 0; r < 4; r++) pk[r] = sp[t][r];
          *(us4*)&So[(size_t)(t * NN + n) * NC + ob] = pk;
        }
      } else {
        // transposed [c][l]: c = ob+r, l = t*NN+n
#pragma unroll
        for (int t = 0; t < NT; t++)
#pragma unroll
          for (int r = 0; r < 4; r++)
            So[(size_t)(ob + r) * NL + t * NN + n] = sp[t][r];
      }
    }
  }
}

// ---------------------------------------------------------------------------
// MFMA Gram, single pass over full K=1024:
//   Mpart[bh][e][dd] = sum_l K[l][e]*V[l][dd].
// KT/VT are [c][l] -> both fragments contiguous us8 loads; LDS-free.
// All products/sums are integers (spikes 0/1) -> fp32-exact, order-free.
__global__ __launch_bounds__(256) void
k_kvM(const unsigned short* __restrict__ STkT,
      const unsigned short* __restrict__ STvT,
      float* __restrict__ Mpart) {
  int bh = blockIdx.x;                        // 64 = b*8 + h
  int b = bh >> 3, h = bh & 7;
  const unsigned short* KT = STkT + ((size_t)(b * NC + h * ND)) * NL;
  const unsigned short* VT = STvT + ((size_t)(b * NC + h * ND)) * NL;
  int tid = threadIdx.x;
  int w = tid >> 6, lane = tid & 63, quad = lane >> 4, l15 = lane & 15;

  f32x4 acc[4];
#pragma unroll
  for (int jj = 0; jj < 4; jj++) acc[jj] = (f32x4){0.f, 0.f, 0.f, 0.f};

#pragma unroll 4
  for (int ks = 0; ks < 32; ks++) {
    int lc = ks * 32 + quad * 8;
    short8v a = *(const short8v*)&KT[(size_t)(w * 16 + l15) * NL + lc];
#pragma unroll
    for (int jj = 0; jj < 4; jj++) {
      short8v bv = *(const short8v*)&VT[(size_t)(jj * 16 + l15) * NL + lc];
      acc[jj] = __builtin_amdgcn_mfma_f32_16x16x32_bf16(a, bv, acc[jj], 0, 0, 0);
    }
  }

  float* Mp = Mpart + (size_t)bh * 4096;
#pragma unroll
  for (int jj = 0; jj < 4; jj++)
#pragma unroll
    for (int r = 0; r < 4; r++)
      Mp[(w * 16 + quad * 4 + r) * ND + jj * 16 + l15] = acc[jj][r];
}

// ---------------------------------------------------------------------------
// MFMA attention: O^T[dd][l] = sum_e (M1+M2)^T[dd][e] * Q[l][e]; spike O>=12.
// M split into two exact bf16 planes (M integer <=1024 — split exact).
// Prologue: single 16KB read of Mpart[bh] (no chunk reduce).
__global__ __launch_bounds__(256) void
k_attn(const unsigned short* __restrict__ STq,
       const float* __restrict__ Mpart,
       unsigned short* __restrict__ STs) {
  __shared__ unsigned short MT1[64 * 64];   // [dd][e], 16B chunks phys = c ^ (dd&7)
  __shared__ unsigned short MT2[64 * 64];
  int lt = blockIdx.x, bh = blockIdx.y;
  int b = bh >> 3, h = bh & 7;
  int tid = threadIdx.x;
  int w = tid >> 6, lane = tid & 63, quad = lane >> 4, l15 = lane & 15;

#pragma unroll
  for (int i = 0; i < 4; i++) {
    int idx4 = tid + i * 256;
    float4 s = ((const float4*)Mpart)[(size_t)bh * 1024 + idx4];
    int e = idx4 >> 4;
    int dd0 = (idx4 * 4) & 63;
    int chunk = e >> 3;
    float sv[4] = {s.x, s.y, s.z, s.w};
#pragma unroll
    for (int r = 0; r < 4; r++) {
      int dd = dd0 + r;
      unsigned short u1 = f2bu(sv[r]);
      unsigned short u2 = f2bu(sv[r] - bu2f(u1));
      int pos = dd * 64 + (((chunk ^ (dd & 7)) << 3) | (e & 7));
      MT1[pos] = u1;
      MT2[pos] = u2;
    }
  }
  __syncthreads();

  const unsigned short* Qp = STq + (size_t)b * NL * NC + h * ND;
  int lbase = lt * 256 + w * 64;

  f32x4 acc[4][4];                           // [ddtile][ltile]
#pragma unroll
  for (int dt = 0; dt < 4; dt++)
#pragma unroll
    for (int j = 0; j < 4; j++) acc[dt][j] = (f32x4){0.f, 0.f, 0.f, 0.f};

#pragma unroll
  for (int ks = 0; ks < 2; ks++) {
    short8v bq[4];
#pragma unroll
    for (int ltile = 0; ltile < 4; ltile++)
      bq[ltile] = *(const short8v*)&Qp[(size_t)(lbase + ltile * 16 + l15) * NC
                                       + ks * 32 + quad * 8];
    int c8 = ks * 4 + quad;
#pragma unroll
    for (int dt = 0; dt < 4; dt++) {
      int dd = dt * 16 + l15;
      int off = dd * 64 + ((c8 ^ (dd & 7)) << 3);
      short8v a1 = *(const short8v*)&MT1[off];
      short8v a2 = *(const short8v*)&MT2[off];
#pragma unroll
      for (int ltile = 0; ltile < 4; ltile++) {
        acc[dt][ltile] = __builtin_amdgcn_mfma_f32_16x16x32_bf16(a1, bq[ltile], acc[dt][ltile], 0, 0, 0);
        acc[dt][ltile] = __builtin_amdgcn_mfma_f32_16x16x32_bf16(a2, bq[ltile], acc[dt][ltile], 0, 0, 0);
      }
    }
  }

  unsigned short* Sp = STs + (size_t)b * NL * NC + h * ND;
#pragma unroll
  for (int dt = 0; dt < 4; dt++)
#pragma unroll
    for (int ltile = 0; ltile < 4; ltile++) {
      int l = lbase + ltile * 16 + l15;
      int dd = dt * 16 + quad * 4;
      us4 pk;
#pragma unroll
      for (int r = 0; r < 4; r++) pk[r] = (acc[dt][ltile][r] >= 12.0f) ? 0x3F80 : 0;
      *(us4*)&Sp[(size_t)l * NC + dd] = pk;
    }
}

// ---------------------------------------------------------------------------
// Final projection: 16x16x32, 128 rows x 64 cols; XCD-grouped swizzle +
// A-register double-buffer (round-11/15 version).
__global__ __launch_bounds__(256) void
k_out(const unsigned short* __restrict__ H2,
      const unsigned short* __restrict__ STs,
      const float* __restrict__ bp, float* __restrict__ out) {
  __shared__ __align__(16) unsigned short sB[2][64 * 64];

  int id = blockIdx.x;                  // 512 = 8 xcd * 64 slot
  int xcd = id & 7, slot = id >> 3;
  int qq = xcd * 64 + slot;             // ordered by (rt, b, l0)
  int rt = qq >> 7;
  int mi = qq & 127;
  int b  = mi >> 4;
  int l0 = (mi & 15) * 64;

  int tid = threadIdx.x;
  int w = tid >> 6, lane = tid & 63, quad = lane >> 4, l15 = lane & 15;
  int xorv = l15 & 7;

  const unsigned short* Sb = STs + (size_t)b * NL * NC;
  const unsigned short* Hbase = H2 + ((size_t)(9 * 4 + rt) * 8) * 8192;  // p=3

  f32x4 acc[2][4];
#pragma unroll
  for (int ri = 0; ri < 2; ri++)
#pragma unroll
    for (int jj = 0; jj < 4; jj++) acc[ri][jj] = (f32x4){0.f, 0.f, 0.f, 0.f};

  short8v A0[2][3][2], A1[2][3][2];

#define OLOADA(DST, K0I)                                                     \
  _Pragma("unroll") for (int ks = 0; ks < 2; ks++) {                         \
    int c8 = ks * 4 + quad;                                                  \
    _Pragma("unroll") for (int j = 0; j < 3; j++) {                          \
      const unsigned short* Hj =                                             \
          Hbase + ((size_t)(j * 4 * 8 + (K0I))) * 8192 + (size_t)c8 * 1024;  \
      DST[ks][j][0] = *(const short8v*)&Hj[(w * 32 + l15) * 8];              \
      DST[ks][j][1] = *(const short8v*)&Hj[(w * 32 + 16 + l15) * 8];         \
    }                                                                        \
  }

  OLOADA(A0, 0);

  us8 breg[2];
  int ccs[2], segs[2];
  size_t bsrc[2];
#pragma unroll
  for (int i = 0; i < 2; i++) {
    int idx = tid + i * 256;
    int cc = idx >> 3, seg = idx & 7;
    ccs[i] = cc; segs[i] = seg;
    bsrc[i] = (size_t)(l0 + cc) * NC + seg * 8;
  }
#pragma unroll
  for (int i = 0; i < 2; i++) breg[i] = *(const us8*)&Sb[bsrc[i]];
#pragma unroll
  for (int i = 0; i < 2; i++)
    *(us8*)&sB[0][ccs[i] * 64 + ((segs[i] ^ (ccs[i] & 7)) << 3)] = breg[i];

#define OBPRE(K0N)                                                           \
  _Pragma("unroll") for (int i = 0; i < 2; i++)                              \
    breg[i] = *(const us8*)&Sb[bsrc[i] + (size_t)(K0N) * 64];

#define OBWRITE(BUFN)                                                        \
  _Pragma("unroll") for (int i = 0; i < 2; i++)                              \
    *(us8*)&sB[BUFN][ccs[i] * 64 + ((segs[i] ^ (ccs[i] & 7)) << 3)] = breg[i];

#define OMFMAS(AR, BUF)                                                      \
  _Pragma("unroll") for (int ks = 0; ks < 2; ks++) {                         \
    int c8 = ks * 4 + quad;                                                  \
    int poff = (c8 ^ xorv) << 3;                                             \
    short8v bf[4];                                                           \
    _Pragma("unroll") for (int jj = 0; jj < 4; jj++)                         \
      bf[jj] = *(const short8v*)&sB[BUF][(jj * 16 + l15) * 64 + poff];       \
    _Pragma("unroll") for (int j = 0; j < 3; j++)                            \
      _Pragma("unroll") for (int jj = 0; jj < 4; jj++) {                     \
        acc[0][jj] = __builtin_amdgcn_mfma_f32_16x16x32_bf16(                \
            AR[ks][j][0], bf[jj], acc[0][jj], 0, 0, 0);                      \
        acc[1][jj] = __builtin_amdgcn_mfma_f32_16x16x32_bf16(                \
            AR[ks][j][1], bf[jj], acc[1][jj], 0, 0, 0);                      \
      }                                                                      \
  }

#define OSTEP(K0I, ACUR, ANXT)                                               \
  __syncthreads();                                                           \
  { if ((K0I) < 7) { OLOADA(ANXT, (K0I) + 1); } }                            \
  { if ((K0I) < 7) { OBPRE((K0I) + 1); } }                                   \
  OMFMAS(ACUR, (K0I) & 1);                                                   \
  { if ((K0I) < 7) { OBWRITE(((K0I) & 1) ^ 1); } }

  OSTEP(0, A0, A1)
  OSTEP(1, A1, A0)
  OSTEP(2, A0, A1)
  OSTEP(3, A1, A0)
  OSTEP(4, A0, A1)
  OSTEP(5, A1, A0)
  OSTEP(6, A0, A1)
  OSTEP(7, A1, A0)

#undef OLOADA
#undef OBPRE
#undef OBWRITE
#undef OMFMAS
#undef OSTEP

#pragma unroll
  for (int ri = 0; ri < 2; ri++) {
    int ob = rt * 128 + w * 32 + ri * 16 + quad * 4;
#pragma unroll
    for (int jj = 0; jj < 4; jj++) {
      int l = l0 + jj * 16 + l15;
#pragma unroll
      for (int r = 0; r < 4; r++)
        out[((size_t)(b * NC + ob + r)) * NL + l] = acc[ri][jj][r] + bp[ob + r];
    }
  }
}

// ---------------------------------------------------------------------------
extern "C" void kernel_launch(void* const* d_in, const int* in_sizes, int n_in,
                              void* d_out, int out_size, void* d_ws, size_t ws_size,
                              hipStream_t stream) {
  (void)in_sizes; (void)n_in; (void)out_size; (void)ws_size;
  const float* x   = (const float*)d_in[0];
  const float* wq  = (const float*)d_in[1];
  const float* wk  = (const float*)d_in[2];
  const float* wv  = (const float*)d_in[3];
  const float* wp  = (const float*)d_in[4];
  const float* bp  = (const float*)d_in[5];
  const float* gq  = (const float*)d_in[6];
  const float* bq  = (const float*)d_in[7];
  const float* mq  = (const float*)d_in[8];
  const float* vq  = (const float*)d_in[9];
  const float* gk  = (const float*)d_in[10];
  const float* bk  = (const float*)d_in[11];
  const float* mk  = (const float*)d_in[12];
  const float* vk  = (const float*)d_in[13];
  const float* gv  = (const float*)d_in[14];
  const float* bv  = (const float*)d_in[15];
  const float* mv  = (const float*)d_in[16];
  const float* vvv = (const float*)d_in[17];
  const float* gp  = (const float*)d_in[18];
  const float* bpn = (const float*)d_in[19];
  const float* mp  = (const float*)d_in[20];
  const float* vp  = (const float*)d_in[21];

  unsigned short* H2   = (unsigned short*)d_ws;
  unsigned short* ST0  = H2 + (size_t)4 * 3 * NC * NC;
  unsigned short* STq  = ST0 + BCL;
  unsigned short* STkT = STq + BCL;
  unsigned short* STvT = STkT + BCL;
  unsigned short* STs  = STvT + BCL;
  float* Mpart = (float*)(STs + BCL);   // 64 * 4096 floats (1 MB)

  dim3 blk(256);
  k_prep<<<1024, blk, 0, stream>>>(wq, wk, wv, wp, x, gp, bpn, mp, vp, H2, ST0);
  k_qkv<<<768, blk, 0, stream>>>(H2, ST0,
      gq, bq, mq, vq, gk, bk, mk, vk, gv, bv, mv, vvv, STq, STkT, STvT);
  k_kvM<<<64, blk, 0, stream>>>(STkT, STvT, Mpart);
  k_attn<<<dim3(4, 64), blk, 0, stream>>>(STq, Mpart, STs);
  k_out<<<512, blk, 0, stream>>>(H2, STs, bp, (float*)d_out);
}

// Round 8
// 192.394 us; speedup vs baseline: 1.0335x; 1.0259x over previous
//
#include <hip/hip_runtime.h>
#include <hip/hip_bf16.h>

// SpikingSelfAttention — round 18: round-15 structure (MFMA Gram, chunked
// k_kvM grid 512) + fixed k_qkv transposed epilogue. The round-15 scalar
// 2B transposed stores caused write-allocate line fills (+30MB FETCH, +11us).
// Now K/V spikes stage through LDS (reuse sB after K-loop) and drain as
// 64B-aligned full-line segments (4x us8 per segment, one thread each) ->
// no partial-line RFO. Numerics bit-identical (pure data movement).

#define NB 8
#define NC 512
#define NT 4
#define NN 256
#define NL 1024
#define NH 8
#define ND 64
#define BCL (NB*NC*NL)

typedef __attribute__((ext_vector_type(8))) short  short8v;
typedef __attribute__((ext_vector_type(8))) unsigned short us8;
typedef __attribute__((ext_vector_type(4))) unsigned short us4;
typedef __attribute__((ext_vector_type(4))) float f32x4;

__device__ __forceinline__ float bu2f(unsigned short u) {
  return __uint_as_float(((unsigned)u) << 16);
}
__device__ __forceinline__ unsigned short f2bu(float f) {   // RNE f32->bf16
  unsigned b = __float_as_uint(f);
  return (unsigned short)((b + 0x7FFFu + ((b >> 16) & 1u)) >> 16);
}

// ---------------------------------------------------------------------------
// k_prep: blocks [0,512) = weight split into fragment-ordered H2;
//         blocks [512,1024) = proj BN+LIF -> ST0[b][l][c] bf16.
// H2 layout: offset = ((((p*3+j)*4+rt)*8+k0i)*8+chunk)*1024 + r*8
__global__ void k_prep(const float* __restrict__ wq, const float* __restrict__ wk,
                       const float* __restrict__ wv, const float* __restrict__ wp,
                       const float* __restrict__ x,
                       const float* __restrict__ g,  const float* __restrict__ bt,
                       const float* __restrict__ mu, const float* __restrict__ var,
                       unsigned short* __restrict__ H2,
                       unsigned short* __restrict__ ST0) {
  if (blockIdx.x < 512) {
    int gi = blockIdx.x * 256 + threadIdx.x;       // (p,o,k8): 4*512*64
    int p = gi >> 15;
    int o = (gi >> 6) & 511;
    int k8 = gi & 63;
    int rt = o >> 7, r = o & 127;
    int k0i = k8 >> 3, chunk = k8 & 7;
    const float* W = (p == 0) ? wq : (p == 1) ? wk : (p == 2) ? wv : wp;
    const float* src = W + (size_t)o * NC + k8 * 8;
    us8 a[3];
#pragma unroll
    for (int i = 0; i < 8; i++) {
      float w = src[i];
      unsigned short u1 = f2bu(w);
      float r1 = w - bu2f(u1);
      unsigned short u2 = f2bu(r1);
      float r2 = r1 - bu2f(u2);
      unsigned short u3 = f2bu(r2);
      a[0][i] = u1; a[1][i] = u2; a[2][i] = u3;
    }
#pragma unroll
    for (int j = 0; j < 3; j++) {
      size_t off = ((size_t)((((p * 3 + j) * 4 + rt) * 8 + k0i) * 8 + chunk)) * 1024
                   + (size_t)r * 8;
      *(us8*)&H2[off] = a[j];
    }
  } else {
    int bidx = blockIdx.x - 512;
    int b  = bidx >> 6;
    int c0 = (bidx & 63) * 8;
    int n  = threadIdx.x;
    unsigned short spk[NT][8];
#pragma unroll
    for (int i = 0; i < 8; i++) {
      int c = c0 + i;
      float inv = g[c] / sqrtf(var[c] + 1e-5f);
      float m = mu[c], be = bt[c];
      const float* xp = x + ((size_t)(b * NC + c)) * NL + n;
      float v = 0.f;
#pragma unroll
      for (int t = 0; t < NT; t++) {
        float y = (xp[t * NN] - m) * inv + be;
        v = v + (y - v) / 1.5f;
        unsigned short s = 0;
        if (v - 1.0f >= 0.f) { s = 0x3F80; v = 0.f; }
        spk[t][i] = s;
      }
    }
#pragma unroll
    for (int t = 0; t < NT; t++) {
      us8 pk;
#pragma unroll
      for (int i = 0; i < 8; i++) pk[i] = spk[t][i];
      *(us8*)&ST0[((size_t)b * NL + t * NN + n) * NC + c0] = pk;
    }
  }
}

// ---------------------------------------------------------------------------
// Fused q/k/v projection + BN + LIF. 16x16x32 MFMA, 128x128 tile, 4x1 wave
// strips. XCD-grouped swizzle + A-register double-buffer. Epilogue: q written
// [l][c]; k,v written TRANSPOSED [c][l] via LDS-staged 64B full-line drains.
__global__ __launch_bounds__(256) void
k_qkv(const unsigned short* __restrict__ H2,
      const unsigned short* __restrict__ ST0,
      const float* __restrict__ gq, const float* __restrict__ bq,
      const float* __restrict__ mq, const float* __restrict__ vq,
      const float* __restrict__ gk, const float* __restrict__ bk,
      const float* __restrict__ mk, const float* __restrict__ vk,
      const float* __restrict__ gv, const float* __restrict__ bv,
      const float* __restrict__ mv, const float* __restrict__ vv,
      unsigned short* __restrict__ STq, unsigned short* __restrict__ STkT,
      unsigned short* __restrict__ STvT) {
  __shared__ __align__(16) unsigned short sB[2][128 * 64];

  int id = blockIdx.x;                  // 768 = 8 xcd * 96 slot
  int xcd = id & 7, slot = id >> 3;
  int qq = xcd * 96 + slot;             // ordered by (p, rt, b, n0)
  int grp = qq >> 6, mi = qq & 63;      // grp = p*4+rt in [0,12)
  int p = grp >> 2, rt = grp & 3;
  int b = mi >> 3;
  int n0 = (mi & 7) * 32;

  int tid = threadIdx.x;
  int w = tid >> 6, lane = tid & 63, quad = lane >> 4, l15 = lane & 15;
  int xorv = l15 & 7;

  const unsigned short* Sb = ST0 + (size_t)b * NL * NC;
  const unsigned short* Hbase = H2 + ((size_t)((p * 3) * 4 + rt) * 8) * 8192;

  f32x4 acc[2][8];
#pragma unroll
  for (int ri = 0; ri < 2; ri++)
#pragma unroll
    for (int jj = 0; jj < 8; jj++) acc[ri][jj] = (f32x4){0.f, 0.f, 0.f, 0.f};

  // A-fragment double-buffer register sets (named, compile-time indexed).
  short8v A0[2][3][2], A1[2][3][2];

#define QLOADA(DST, K0I)                                                     \
  _Pragma("unroll") for (int ks = 0; ks < 2; ks++) {                         \
    int c8 = ks * 4 + quad;                                                  \
    _Pragma("unroll") for (int j = 0; j < 3; j++) {                          \
      const unsigned short* Hj =                                             \
          Hbase + ((size_t)(j * 4 * 8 + (K0I))) * 8192 + (size_t)c8 * 1024;  \
      DST[ks][j][0] = *(const short8v*)&Hj[(w * 32 + l15) * 8];              \
      DST[ks][j][1] = *(const short8v*)&Hj[(w * 32 + 16 + l15) * 8];         \
    }                                                                        \
  }

  QLOADA(A0, 0);                        // prologue A; latency hides under B-stage

  us8 breg[4];
  int ccs[4], segs[4];
  size_t bsrc[4];
#pragma unroll
  for (int i = 0; i < 4; i++) {
    int idx = tid + i * 256;
    int cc = idx >> 3, seg = idx & 7;
    int t = (cc >> 4) & 3, nn = (cc & 15) | ((cc >> 6) << 4);
    ccs[i] = cc; segs[i] = seg;
    bsrc[i] = (size_t)(t * NN + n0 + nn) * NC + seg * 8;
  }
#pragma unroll
  for (int i = 0; i < 4; i++) breg[i] = *(const us8*)&Sb[bsrc[i]];      // k0=0
#pragma unroll
  for (int i = 0; i < 4; i++)
    *(us8*)&sB[0][ccs[i] * 64 + ((segs[i] ^ (ccs[i] & 7)) << 3)] = breg[i];

#define QBPRE(K0N)                                                           \
  _Pragma("unroll") for (int i = 0; i < 4; i++)                              \
    breg[i] = *(const us8*)&Sb[bsrc[i] + (size_t)(K0N) * 64];

#define QBWRITE(BUFN)                                                        \
  _Pragma("unroll") for (int i = 0; i < 4; i++)                              \
    *(us8*)&sB[BUFN][ccs[i] * 64 + ((segs[i] ^ (ccs[i] & 7)) << 3)] = breg[i];

#define QMFMAS(AR, BUF)                                                      \
  _Pragma("unroll") for (int ks = 0; ks < 2; ks++) {                         \
    int c8 = ks * 4 + quad;                                                  \
    int poff = (c8 ^ xorv) << 3;                                             \
    short8v bf[8];                                                           \
    _Pragma("unroll") for (int jj = 0; jj < 8; jj++)                         \
      bf[jj] = *(const short8v*)&sB[BUF][(jj * 16 + l15) * 64 + poff];       \
    _Pragma("unroll") for (int j = 0; j < 3; j++)                            \
      _Pragma("unroll") for (int jj = 0; jj < 8; jj++) {                     \
        acc[0][jj] = __builtin_amdgcn_mfma_f32_16x16x32_bf16(                \
            AR[ks][j][0], bf[jj], acc[0][jj], 0, 0, 0);                      \
        acc[1][jj] = __builtin_amdgcn_mfma_f32_16x16x32_bf16(                \
            AR[ks][j][1], bf[jj], acc[1][jj], 0, 0, 0);                      \
      }                                                                      \
  }

#define QSTEP(K0I, ACUR, ANXT)                                               \
  __syncthreads();                                                           \
  { if ((K0I) < 7) { QLOADA(ANXT, (K0I) + 1); } }                            \
  { if ((K0I) < 7) { QBPRE((K0I) + 1); } }                                   \
  QMFMAS(ACUR, (K0I) & 1);                                                   \
  { if ((K0I) < 7) { QBWRITE(((K0I) & 1) ^ 1); } }

  QSTEP(0, A0, A1)
  QSTEP(1, A1, A0)
  QSTEP(2, A0, A1)
  QSTEP(3, A1, A0)
  QSTEP(4, A0, A1)
  QSTEP(5, A1, A0)
  QSTEP(6, A0, A1)
  QSTEP(7, A1, A0)

#undef QLOADA
#undef QBPRE
#undef QBWRITE
#undef QMFMAS
#undef QSTEP

  const float *g, *bb, *mpt, *vr;
  unsigned short* So;
  if (p == 0)      { g = gq; bb = bq; mpt = mq; vr = vq; So = STq; }
  else if (p == 1) { g = gk; bb = bk; mpt = mk; vr = vk; So = STkT; }
  else             { g = gv; bb = bv; mpt = mv; vr = vv; So = STvT; }
  So += (size_t)b * NL * NC;

  // Compute all spikes into registers first.
  unsigned short spa[2][2][4][4];       // [ri][nh][t][r]
#pragma unroll
  for (int ri = 0; ri < 2; ri++) {
    int ob = rt * 128 + w * 32 + ri * 16 + quad * 4;
    float av[4], mvv[4], bvv[4];
#pragma unroll
    for (int r = 0; r < 4; r++) {
      av[r]  = g[ob + r] / sqrtf(vr[ob + r] + 1e-5f);
      mvv[r] = mpt[ob + r];
      bvv[r] = bb[ob + r];
    }
#pragma unroll
    for (int nh = 0; nh < 2; nh++) {
#pragma unroll
      for (int r = 0; r < 4; r++) {
        float vmem = 0.f;
#pragma unroll
        for (int t = 0; t < NT; t++) {
          float y = (acc[ri][nh * 4 + t][r] - mvv[r]) * av[r] + bvv[r];
          vmem = vmem + (y - vmem) / 1.5f;
          unsigned short s = 0;
          if (vmem - 1.0f >= 0.f) { s = 0x3F80; vmem = 0.f; }
          spa[ri][nh][t][r] = s;
        }
      }
    }
  }

  __syncthreads();                      // K-loop sB reads done; safe to reuse

  if (p == 0) {
#pragma unroll
    for (int ri = 0; ri < 2; ri++) {
      int ob = rt * 128 + w * 32 + ri * 16 + quad * 4;
#pragma unroll
      for (int nh = 0; nh < 2; nh++) {
        int n = n0 + (nh << 4) + l15;
#pragma unroll
        for (int t = 0; t < NT; t++) {
          us4 pk;
#pragma unroll
          for (int r = 0; r < 4; r++) pk[r] = spa[ri][nh][t][r];
          *(us4*)&So[(size_t)(t * NN + n) * NC + ob] = pk;
        }
      }
    }
  } else {
    // Stage [c 128][l-packed 128] tile in LDS (XOR-swizzled 16B granules),
    // then drain 64B full-line segments: seg (c,t) -> So[c][t*256+n0 .. +32].
    unsigned short* sT = &sB[0][0];     // 32 KB, exactly sB
#pragma unroll
    for (int ri = 0; ri < 2; ri++)
#pragma unroll
      for (int nh = 0; nh < 2; nh++)
#pragma unroll
        for (int t = 0; t < 4; t++)
#pragma unroll
          for (int r = 0; r < 4; r++) {
            int row = w * 32 + ri * 16 + quad * 4 + r;
            int col = t * 32 + (nh << 4) + l15;
            int phys = (((col >> 3) ^ (row & 7)) << 3) | (col & 7);
            sT[row * 128 + phys] = spa[ri][nh][t][r];
          }
    __syncthreads();
#pragma unroll
    for (int ss = 0; ss < 2; ss++) {
      int s = tid + ss * 256;           // 512 segs = 128 c x 4 t
      int c = s >> 2, t = s & 3;
#pragma unroll
      for (int i = 0; i < 4; i++) {
        int g8 = t * 4 + i;
        us8 v = *(const us8*)&sT[c * 128 + ((g8 ^ (c & 7)) << 3)];
        *(us8*)&So[(size_t)(rt * 128 + c) * NL + t * 256 + n0 + i * 8] = v;
      }
    }
  }
}

// ---------------------------------------------------------------------------
// MFMA Gram (chunked): Mpart[ch][bh][e][dd] = sum_{l in 128-chunk} K[l][e]*V[l][dd].
// KT/VT are [c][l] -> both fragments contiguous us8 loads; LDS-free.
// All products/sums are integers (spikes 0/1) -> fp32-exact, order-free.
__global__ __launch_bounds__(256) void
k_kvM(const unsigned short* __restrict__ STkT,
      const unsigned short* __restrict__ STvT,
      float* __restrict__ Mpart) {
  int bh = blockIdx.x, ch = blockIdx.y;       // ch 0..7
  int b = bh >> 3, h = bh & 7;
  const unsigned short* KT = STkT + ((size_t)(b * NC + h * ND)) * NL;
  const unsigned short* VT = STvT + ((size_t)(b * NC + h * ND)) * NL;
  int tid = threadIdx.x;
  int w = tid >> 6, lane = tid & 63, quad = lane >> 4, l15 = lane & 15;
  int lb = ch * 128;

  f32x4 acc[4];
#pragma unroll
  for (int jj = 0; jj < 4; jj++) acc[jj] = (f32x4){0.f, 0.f, 0.f, 0.f};

#pragma unroll
  for (int ks = 0; ks < 4; ks++) {
    int lc = lb + ks * 32 + quad * 8;
    short8v a = *(const short8v*)&KT[(size_t)(w * 16 + l15) * NL + lc];
#pragma unroll
    for (int jj = 0; jj < 4; jj++) {
      short8v bv = *(const short8v*)&VT[(size_t)(jj * 16 + l15) * NL + lc];
      acc[jj] = __builtin_amdgcn_mfma_f32_16x16x32_bf16(a, bv, acc[jj], 0, 0, 0);
    }
  }

  float* Mp = Mpart + ((size_t)ch * 64 + bh) * 4096;
#pragma unroll
  for (int jj = 0; jj < 4; jj++)
#pragma unroll
    for (int r = 0; r < 4; r++)
      Mp[(w * 16 + quad * 4 + r) * ND + jj * 16 + l15] = acc[jj][r];
}

// ---------------------------------------------------------------------------
// MFMA attention: O^T[dd][l] = sum_e (M1+M2)^T[dd][e] * Q[l][e]; spike O>=12.
// M split into two exact bf16 planes (M integer <=1024 — split exact).
__global__ __launch_bounds__(256) void
k_attn(const unsigned short* __restrict__ STq,
       const float* __restrict__ Mpart,
       unsigned short* __restrict__ STs) {
  __shared__ unsigned short MT1[64 * 64];   // [dd][e], 16B chunks phys = c ^ (dd&7)
  __shared__ unsigned short MT2[64 * 64];
  int lt = blockIdx.x, bh = blockIdx.y;
  int b = bh >> 3, h = bh & 7;
  int tid = threadIdx.x;
  int w = tid >> 6, lane = tid & 63, quad = lane >> 4, l15 = lane & 15;

#pragma unroll
  for (int i = 0; i < 4; i++) {
    int idx4 = tid + i * 256;
    float4 s = ((const float4*)Mpart)[(size_t)bh * 1024 + idx4];
#pragma unroll
    for (int ch = 1; ch < 8; ch++) {
      float4 t = ((const float4*)Mpart)[((size_t)ch * 64 + bh) * 1024 + idx4];
      s.x += t.x; s.y += t.y; s.z += t.z; s.w += t.w;
    }
    int e = idx4 >> 4;
    int dd0 = (idx4 * 4) & 63;
    int chunk = e >> 3;
    float sv[4] = {s.x, s.y, s.z, s.w};
#pragma unroll
    for (int r = 0; r < 4; r++) {
      int dd = dd0 + r;
      unsigned short u1 = f2bu(sv[r]);
      unsigned short u2 = f2bu(sv[r] - bu2f(u1));
      int pos = dd * 64 + (((chunk ^ (dd & 7)) << 3) | (e & 7));
      MT1[pos] = u1;
      MT2[pos] = u2;
    }
  }
  __syncthreads();

  const unsigned short* Qp = STq + (size_t)b * NL * NC + h * ND;
  int lbase = lt * 256 + w * 64;

  f32x4 acc[4][4];                           // [ddtile][ltile]
#pragma unroll
  for (int dt = 0; dt < 4; dt++)
#pragma unroll
    for (int j = 0; j < 4; j++) acc[dt][j] = (f32x4){0.f, 0.f, 0.f, 0.f};

#pragma unroll
  for (int ks = 0; ks < 2; ks++) {
    short8v bq[4];
#pragma unroll
    for (int ltile = 0; ltile < 4; ltile++)
      bq[ltile] = *(const short8v*)&Qp[(size_t)(lbase + ltile * 16 + l15) * NC
                                       + ks * 32 + quad * 8];
    int c8 = ks * 4 + quad;
#pragma unroll
    for (int dt = 0; dt < 4; dt++) {
      int dd = dt * 16 + l15;
      int off = dd * 64 + ((c8 ^ (dd & 7)) << 3);
      short8v a1 = *(const short8v*)&MT1[off];
      short8v a2 = *(const short8v*)&MT2[off];
#pragma unroll
      for (int ltile = 0; ltile < 4; ltile++) {
        acc[dt][ltile] = __builtin_amdgcn_mfma_f32_16x16x32_bf16(a1, bq[ltile], acc[dt][ltile], 0, 0, 0);
        acc[dt][ltile] = __builtin_amdgcn_mfma_f32_16x16x32_bf16(a2, bq[ltile], acc[dt][ltile], 0, 0, 0);
      }
    }
  }

  unsigned short* Sp = STs + (size_t)b * NL * NC + h * ND;
#pragma unroll
  for (int dt = 0; dt < 4; dt++)
#pragma unroll
    for (int ltile = 0; ltile < 4; ltile++) {
      int l = lbase + ltile * 16 + l15;
      int dd = dt * 16 + quad * 4;
      us4 pk;
#pragma unroll
      for (int r = 0; r < 4; r++) pk[r] = (acc[dt][ltile][r] >= 12.0f) ? 0x3F80 : 0;
      *(us4*)&Sp[(size_t)l * NC + dd] = pk;
    }
}

// ---------------------------------------------------------------------------
// Final projection: 16x16x32, 128 rows x 64 cols; XCD-grouped swizzle +
// A-register double-buffer (round-11/15 version).
__global__ __launch_bounds__(256) void
k_out(const unsigned short* __restrict__ H2,
      const unsigned short* __restrict__ STs,
      const float* __restrict__ bp, float* __restrict__ out) {
  __shared__ __align__(16) unsigned short sB[2][64 * 64];

  int id = blockIdx.x;                  // 512 = 8 xcd * 64 slot
  int xcd = id & 7, slot = id >> 3;
  int qq = xcd * 64 + slot;             // ordered by (rt, b, l0)
  int rt = qq >> 7;
  int mi = qq & 127;
  int b  = mi >> 4;
  int l0 = (mi & 15) * 64;

  int tid = threadIdx.x;
  int w = tid >> 6, lane = tid & 63, quad = lane >> 4, l15 = lane & 15;
  int xorv = l15 & 7;

  const unsigned short* Sb = STs + (size_t)b * NL * NC;
  const unsigned short* Hbase = H2 + ((size_t)(9 * 4 + rt) * 8) * 8192;  // p=3

  f32x4 acc[2][4];
#pragma unroll
  for (int ri = 0; ri < 2; ri++)
#pragma unroll
    for (int jj = 0; jj < 4; jj++) acc[ri][jj] = (f32x4){0.f, 0.f, 0.f, 0.f};

  short8v A0[2][3][2], A1[2][3][2];

#define OLOADA(DST, K0I)                                                     \
  _Pragma("unroll") for (int ks = 0; ks < 2; ks++) {                         \
    int c8 = ks * 4 + quad;                                                  \
    _Pragma("unroll") for (int j = 0; j < 3; j++) {                          \
      const unsigned short* Hj =                                             \
          Hbase + ((size_t)(j * 4 * 8 + (K0I))) * 8192 + (size_t)c8 * 1024;  \
      DST[ks][j][0] = *(const short8v*)&Hj[(w * 32 + l15) * 8];              \
      DST[ks][j][1] = *(const short8v*)&Hj[(w * 32 + 16 + l15) * 8];         \
    }                                                                        \
  }

  OLOADA(A0, 0);

  us8 breg[2];
  int ccs[2], segs[2];
  size_t bsrc[2];
#pragma unroll
  for (int i = 0; i < 2; i++) {
    int idx = tid + i * 256;
    int cc = idx >> 3, seg = idx & 7;
    ccs[i] = cc; segs[i] = seg;
    bsrc[i] = (size_t)(l0 + cc) * NC + seg * 8;
  }
#pragma unroll
  for (int i = 0; i < 2; i++) breg[i] = *(const us8*)&Sb[bsrc[i]];
#pragma unroll
  for (int i = 0; i < 2; i++)
    *(us8*)&sB[0][ccs[i] * 64 + ((segs[i] ^ (ccs[i] & 7)) << 3)] = breg[i];

#define OBPRE(K0N)                                                           \
  _Pragma("unroll") for (int i = 0; i < 2; i++)                              \
    breg[i] = *(const us8*)&Sb[bsrc[i] + (size_t)(K0N) * 64];

#define OBWRITE(BUFN)                                                        \
  _Pragma("unroll") for (int i = 0; i < 2; i++)                              \
    *(us8*)&sB[BUFN][ccs[i] * 64 + ((segs[i] ^ (ccs[i] & 7)) << 3)] = breg[i];

#define OMFMAS(AR, BUF)                                                      \
  _Pragma("unroll") for (int ks = 0; ks < 2; ks++) {                         \
    int c8 = ks * 4 + quad;                                                  \
    int poff = (c8 ^ xorv) << 3;                                             \
    short8v bf[4];                                                           \
    _Pragma("unroll") for (int jj = 0; jj < 4; jj++)                         \
      bf[jj] = *(const short8v*)&sB[BUF][(jj * 16 + l15) * 64 + poff];       \
    _Pragma("unroll") for (int j = 0; j < 3; j++)                            \
      _Pragma("unroll") for (int jj = 0; jj < 4; jj++) {                     \
        acc[0][jj] = __builtin_amdgcn_mfma_f32_16x16x32_bf16(                \
            AR[ks][j][0], bf[jj], acc[0][jj], 0, 0, 0);                      \
        acc[1][jj] = __builtin_amdgcn_mfma_f32_16x16x32_bf16(                \
            AR[ks][j][1], bf[jj], acc[1][jj], 0, 0, 0);                      \
      }                                                                      \
  }

#define OSTEP(K0I, ACUR, ANXT)                                               \
  __syncthreads();                                                           \
  { if ((K0I) < 7) { OLOADA(ANXT, (K0I) + 1); } }                            \
  { if ((K0I) < 7) { OBPRE((K0I) + 1); } }                                   \
  OMFMAS(ACUR, (K0I) & 1);                                                   \
  { if ((K0I) < 7) { OBWRITE(((K0I) & 1) ^ 1); } }

  OSTEP(0, A0, A1)
  OSTEP(1, A1, A0)
  OSTEP(2, A0, A1)
  OSTEP(3, A1, A0)
  OSTEP(4, A0, A1)
  OSTEP(5, A1, A0)
  OSTEP(6, A0, A1)
  OSTEP(7, A1, A0)

#undef OLOADA
#undef OBPRE
#undef OBWRITE
#undef OMFMAS
#undef OSTEP

#pragma unroll
  for (int ri = 0; ri < 2; ri++) {
    int ob = rt * 128 + w * 32 + ri * 16 + quad * 4;
#pragma unroll
    for (int jj = 0; jj < 4; jj++) {
      int l = l0 + jj * 16 + l15;
#pragma unroll
      for (int r = 0; r < 4; r++)
        out[((size_t)(b * NC + ob + r)) * NL + l] = acc[ri][jj][r] + bp[ob + r];
    }
  }
}

// ---------------------------------------------------------------------------
extern "C" void kernel_launch(void* const* d_in, const int* in_sizes, int n_in,
                              void* d_out, int out_size, void* d_ws, size_t ws_size,
                              hipStream_t stream) {
  (void)in_sizes; (void)n_in; (void)out_size; (void)ws_size;
  const float* x   = (const float*)d_in[0];
  const float* wq  = (const float*)d_in[1];
  const float* wk  = (const float*)d_in[2];
  const float* wv  = (const float*)d_in[3];
  const float* wp  = (const float*)d_in[4];
  const float* bp  = (const float*)d_in[5];
  const float* gq  = (const float*)d_in[6];
  const float* bq  = (const float*)d_in[7];
  const float* mq  = (const float*)d_in[8];
  const float* vq  = (const float*)d_in[9];
  const float* gk  = (const float*)d_in[10];
  const float* bk  = (const float*)d_in[11];
  const float* mk  = (const float*)d_in[12];
  const float* vk  = (const float*)d_in[13];
  const float* gv  = (const float*)d_in[14];
  const float* bv  = (const float*)d_in[15];
  const float* mv  = (const float*)d_in[16];
  const float* vvv = (const float*)d_in[17];
  const float* gp  = (const float*)d_in[18];
  const float* bpn = (const float*)d_in[19];
  const float* mp  = (const float*)d_in[20];
  const float* vp  = (const float*)d_in[21];

  unsigned short* H2   = (unsigned short*)d_ws;
  unsigned short* ST0  = H2 + (size_t)4 * 3 * NC * NC;
  unsigned short* STq  = ST0 + BCL;
  unsigned short* STkT = STq + BCL;
  unsigned short* STvT = STkT + BCL;
  unsigned short* STs  = STvT + BCL;
  float* Mpart = (float*)(STs + BCL);

  dim3 blk(256);
  k_prep<<<1024, blk, 0, stream>>>(wq, wk, wv, wp, x, gp, bpn, mp, vp, H2, ST0);
  k_qkv<<<768, blk, 0, stream>>>(H2, ST0,
      gq, bq, mq, vq, gk, bk, mk, vk, gv, bv, mv, vvv, STq, STkT, STvT);
  k_kvM<<<dim3(64, 8), blk, 0, stream>>>(STkT, STvT, Mpart);
  k_attn<<<dim3(4, 64), blk, 0, stream>>>(STq, Mpart, STs);
  k_out<<<512, blk, 0, stream>>>(H2, STs, bp, (float*)d_out);
}

// Round 9
// 187.762 us; speedup vs baseline: 1.0590x; 1.0247x over previous
//
#include <hip/hip_runtime.h>
#include <hip/hip_bf16.h>

// SpikingSelfAttention — round 19: r18 base (LDS-staged transposed k_qkv
// epilogue, MFMA Gram) + tail-kernel occupancy fix:
//  - new k_red: one-time 8-chunk Mpart reduction -> Msum (was re-done by all
//    256 k_attn blocks: 32MB -> 9.4MB traffic).
//  - k_attn: grid (8,64)=512 blocks (2/CU, 8 waves/CU; was 1/CU), prologue
//    reads a single 16KB Msum slice. Same MFMA chain per output -> numerics
//    bit-identical.

#define NB 8
#define NC 512
#define NT 4
#define NN 256
#define NL 1024
#define NH 8
#define ND 64
#define BCL (NB*NC*NL)

typedef __attribute__((ext_vector_type(8))) short  short8v;
typedef __attribute__((ext_vector_type(8))) unsigned short us8;
typedef __attribute__((ext_vector_type(4))) unsigned short us4;
typedef __attribute__((ext_vector_type(4))) float f32x4;

__device__ __forceinline__ float bu2f(unsigned short u) {
  return __uint_as_float(((unsigned)u) << 16);
}
__device__ __forceinline__ unsigned short f2bu(float f) {   // RNE f32->bf16
  unsigned b = __float_as_uint(f);
  return (unsigned short)((b + 0x7FFFu + ((b >> 16) & 1u)) >> 16);
}

// ---------------------------------------------------------------------------
// k_prep: blocks [0,512) = weight split into fragment-ordered H2;
//         blocks [512,1024) = proj BN+LIF -> ST0[b][l][c] bf16.
// H2 layout: offset = ((((p*3+j)*4+rt)*8+k0i)*8+chunk)*1024 + r*8
__global__ void k_prep(const float* __restrict__ wq, const float* __restrict__ wk,
                       const float* __restrict__ wv, const float* __restrict__ wp,
                       const float* __restrict__ x,
                       const float* __restrict__ g,  const float* __restrict__ bt,
                       const float* __restrict__ mu, const float* __restrict__ var,
                       unsigned short* __restrict__ H2,
                       unsigned short* __restrict__ ST0) {
  if (blockIdx.x < 512) {
    int gi = blockIdx.x * 256 + threadIdx.x;       // (p,o,k8): 4*512*64
    int p = gi >> 15;
    int o = (gi >> 6) & 511;
    int k8 = gi & 63;
    int rt = o >> 7, r = o & 127;
    int k0i = k8 >> 3, chunk = k8 & 7;
    const float* W = (p == 0) ? wq : (p == 1) ? wk : (p == 2) ? wv : wp;
    const float* src = W + (size_t)o * NC + k8 * 8;
    us8 a[3];
#pragma unroll
    for (int i = 0; i < 8; i++) {
      float w = src[i];
      unsigned short u1 = f2bu(w);
      float r1 = w - bu2f(u1);
      unsigned short u2 = f2bu(r1);
      float r2 = r1 - bu2f(u2);
      unsigned short u3 = f2bu(r2);
      a[0][i] = u1; a[1][i] = u2; a[2][i] = u3;
    }
#pragma unroll
    for (int j = 0; j < 3; j++) {
      size_t off = ((size_t)((((p * 3 + j) * 4 + rt) * 8 + k0i) * 8 + chunk)) * 1024
                   + (size_t)r * 8;
      *(us8*)&H2[off] = a[j];
    }
  } else {
    int bidx = blockIdx.x - 512;
    int b  = bidx >> 6;
    int c0 = (bidx & 63) * 8;
    int n  = threadIdx.x;
    unsigned short spk[NT][8];
#pragma unroll
    for (int i = 0; i < 8; i++) {
      int c = c0 + i;
      float inv = g[c] / sqrtf(var[c] + 1e-5f);
      float m = mu[c], be = bt[c];
      const float* xp = x + ((size_t)(b * NC + c)) * NL + n;
      float v = 0.f;
#pragma unroll
      for (int t = 0; t < NT; t++) {
        float y = (xp[t * NN] - m) * inv + be;
        v = v + (y - v) / 1.5f;
        unsigned short s = 0;
        if (v - 1.0f >= 0.f) { s = 0x3F80; v = 0.f; }
        spk[t][i] = s;
      }
    }
#pragma unroll
    for (int t = 0; t < NT; t++) {
      us8 pk;
#pragma unroll
      for (int i = 0; i < 8; i++) pk[i] = spk[t][i];
      *(us8*)&ST0[((size_t)b * NL + t * NN + n) * NC + c0] = pk;
    }
  }
}

// ---------------------------------------------------------------------------
// Fused q/k/v projection + BN + LIF. 16x16x32 MFMA, 128x128 tile, 4x1 wave
// strips. XCD-grouped swizzle + A-register double-buffer. Epilogue: q written
// [l][c]; k,v written TRANSPOSED [c][l] via LDS-staged 64B full-line drains.
__global__ __launch_bounds__(256) void
k_qkv(const unsigned short* __restrict__ H2,
      const unsigned short* __restrict__ ST0,
      const float* __restrict__ gq, const float* __restrict__ bq,
      const float* __restrict__ mq, const float* __restrict__ vq,
      const float* __restrict__ gk, const float* __restrict__ bk,
      const float* __restrict__ mk, const float* __restrict__ vk,
      const float* __restrict__ gv, const float* __restrict__ bv,
      const float* __restrict__ mv, const float* __restrict__ vv,
      unsigned short* __restrict__ STq, unsigned short* __restrict__ STkT,
      unsigned short* __restrict__ STvT) {
  __shared__ __align__(16) unsigned short sB[2][128 * 64];

  int id = blockIdx.x;                  // 768 = 8 xcd * 96 slot
  int xcd = id & 7, slot = id >> 3;
  int qq = xcd * 96 + slot;             // ordered by (p, rt, b, n0)
  int grp = qq >> 6, mi = qq & 63;      // grp = p*4+rt in [0,12)
  int p = grp >> 2, rt = grp & 3;
  int b = mi >> 3;
  int n0 = (mi & 7) * 32;

  int tid = threadIdx.x;
  int w = tid >> 6, lane = tid & 63, quad = lane >> 4, l15 = lane & 15;
  int xorv = l15 & 7;

  const unsigned short* Sb = ST0 + (size_t)b * NL * NC;
  const unsigned short* Hbase = H2 + ((size_t)((p * 3) * 4 + rt) * 8) * 8192;

  f32x4 acc[2][8];
#pragma unroll
  for (int ri = 0; ri < 2; ri++)
#pragma unroll
    for (int jj = 0; jj < 8; jj++) acc[ri][jj] = (f32x4){0.f, 0.f, 0.f, 0.f};

  // A-fragment double-buffer register sets (named, compile-time indexed).
  short8v A0[2][3][2], A1[2][3][2];

#define QLOADA(DST, K0I)                                                     \
  _Pragma("unroll") for (int ks = 0; ks < 2; ks++) {                         \
    int c8 = ks * 4 + quad;                                                  \
    _Pragma("unroll") for (int j = 0; j < 3; j++) {                          \
      const unsigned short* Hj =                                             \
          Hbase + ((size_t)(j * 4 * 8 + (K0I))) * 8192 + (size_t)c8 * 1024;  \
      DST[ks][j][0] = *(const short8v*)&Hj[(w * 32 + l15) * 8];              \
      DST[ks][j][1] = *(const short8v*)&Hj[(w * 32 + 16 + l15) * 8];         \
    }                                                                        \
  }

  QLOADA(A0, 0);                        // prologue A; latency hides under B-stage

  us8 breg[4];
  int ccs[4], segs[4];
  size_t bsrc[4];
#pragma unroll
  for (int i = 0; i < 4; i++) {
    int idx = tid + i * 256;
    int cc = idx >> 3, seg = idx & 7;
    int t = (cc >> 4) & 3, nn = (cc & 15) | ((cc >> 6) << 4);
    ccs[i] = cc; segs[i] = seg;
    bsrc[i] = (size_t)(t * NN + n0 + nn) * NC + seg * 8;
  }
#pragma unroll
  for (int i = 0; i < 4; i++) breg[i] = *(const us8*)&Sb[bsrc[i]];      // k0=0
#pragma unroll
  for (int i = 0; i < 4; i++)
    *(us8*)&sB[0][ccs[i] * 64 + ((segs[i] ^ (ccs[i] & 7)) << 3)] = breg[i];

#define QBPRE(K0N)                                                           \
  _Pragma("unroll") for (int i = 0; i < 4; i++)                              \
    breg[i] = *(const us8*)&Sb[bsrc[i] + (size_t)(K0N) * 64];

#define QBWRITE(BUFN)                                                        \
  _Pragma("unroll") for (int i = 0; i < 4; i++)                              \
    *(us8*)&sB[BUFN][ccs[i] * 64 + ((segs[i] ^ (ccs[i] & 7)) << 3)] = breg[i];

#define QMFMAS(AR, BUF)                                                      \
  _Pragma("unroll") for (int ks = 0; ks < 2; ks++) {                         \
    int c8 = ks * 4 + quad;                                                  \
    int poff = (c8 ^ xorv) << 3;                                             \
    short8v bf[8];                                                           \
    _Pragma("unroll") for (int jj = 0; jj < 8; jj++)                         \
      bf[jj] = *(const short8v*)&sB[BUF][(jj * 16 + l15) * 64 + poff];       \
    _Pragma("unroll") for (int j = 0; j < 3; j++)                            \
      _Pragma("unroll") for (int jj = 0; jj < 8; jj++) {                     \
        acc[0][jj] = __builtin_amdgcn_mfma_f32_16x16x32_bf16(                \
            AR[ks][j][0], bf[jj], acc[0][jj], 0, 0, 0);                      \
        acc[1][jj] = __builtin_amdgcn_mfma_f32_16x16x32_bf16(                \
            AR[ks][j][1], bf[jj], acc[1][jj], 0, 0, 0);                      \
      }                                                                      \
  }

#define QSTEP(K0I, ACUR, ANXT)                                               \
  __syncthreads();                                                           \
  { if ((K0I) < 7) { QLOADA(ANXT, (K0I) + 1); } }                            \
  { if ((K0I) < 7) { QBPRE((K0I) + 1); } }                                   \
  QMFMAS(ACUR, (K0I) & 1);                                                   \
  { if ((K0I) < 7) { QBWRITE(((K0I) & 1) ^ 1); } }

  QSTEP(0, A0, A1)
  QSTEP(1, A1, A0)
  QSTEP(2, A0, A1)
  QSTEP(3, A1, A0)
  QSTEP(4, A0, A1)
  QSTEP(5, A1, A0)
  QSTEP(6, A0, A1)
  QSTEP(7, A1, A0)

#undef QLOADA
#undef QBPRE
#undef QBWRITE
#undef QMFMAS
#undef QSTEP

  const float *g, *bb, *mpt, *vr;
  unsigned short* So;
  if (p == 0)      { g = gq; bb = bq; mpt = mq; vr = vq; So = STq; }
  else if (p == 1) { g = gk; bb = bk; mpt = mk; vr = vk; So = STkT; }
  else             { g = gv; bb = bv; mpt = mv; vr = vv; So = STvT; }
  So += (size_t)b * NL * NC;

  // Compute all spikes into registers first.
  unsigned short spa[2][2][4][4];       // [ri][nh][t][r]
#pragma unroll
  for (int ri = 0; ri < 2; ri++) {
    int ob = rt * 128 + w * 32 + ri * 16 + quad * 4;
    float av[4], mvv[4], bvv[4];
#pragma unroll
    for (int r = 0; r < 4; r++) {
      av[r]  = g[ob + r] / sqrtf(vr[ob + r] + 1e-5f);
      mvv[r] = mpt[ob + r];
      bvv[r] = bb[ob + r];
    }
#pragma unroll
    for (int nh = 0; nh < 2; nh++) {
#pragma unroll
      for (int r = 0; r < 4; r++) {
        float vmem = 0.f;
#pragma unroll
        for (int t = 0; t < NT; t++) {
          float y = (acc[ri][nh * 4 + t][r] - mvv[r]) * av[r] + bvv[r];
          vmem = vmem + (y - vmem) / 1.5f;
          unsigned short s = 0;
          if (vmem - 1.0f >= 0.f) { s = 0x3F80; vmem = 0.f; }
          spa[ri][nh][t][r] = s;
        }
      }
    }
  }

  __syncthreads();                      // K-loop sB reads done; safe to reuse

  if (p == 0) {
#pragma unroll
    for (int ri = 0; ri < 2; ri++) {
      int ob = rt * 128 + w * 32 + ri * 16 + quad * 4;
#pragma unroll
      for (int nh = 0; nh < 2; nh++) {
        int n = n0 + (nh << 4) + l15;
#pragma unroll
        for (int t = 0; t < NT; t++) {
          us4 pk;
#pragma unroll
          for (int r = 0; r < 4; r++) pk[r] = spa[ri][nh][t][r];
          *(us4*)&So[(size_t)(t * NN + n) * NC + ob] = pk;
        }
      }
    }
  } else {
    // Stage [c 128][l-packed 128] tile in LDS (XOR-swizzled 16B granules),
    // then drain 64B full-line segments: seg (c,t) -> So[c][t*256+n0 .. +32].
    unsigned short* sT = &sB[0][0];     // 32 KB, exactly sB
#pragma unroll
    for (int ri = 0; ri < 2; ri++)
#pragma unroll
      for (int nh = 0; nh < 2; nh++)
#pragma unroll
        for (int t = 0; t < 4; t++)
#pragma unroll
          for (int r = 0; r < 4; r++) {
            int row = w * 32 + ri * 16 + quad * 4 + r;
            int col = t * 32 + (nh << 4) + l15;
            int phys = (((col >> 3) ^ (row & 7)) << 3) | (col & 7);
            sT[row * 128 + phys] = spa[ri][nh][t][r];
          }
    __syncthreads();
#pragma unroll
    for (int ss = 0; ss < 2; ss++) {
      int s = tid + ss * 256;           // 512 segs = 128 c x 4 t
      int c = s >> 2, t = s & 3;
#pragma unroll
      for (int i = 0; i < 4; i++) {
        int g8 = t * 4 + i;
        us8 v = *(const us8*)&sT[c * 128 + ((g8 ^ (c & 7)) << 3)];
        *(us8*)&So[(size_t)(rt * 128 + c) * NL + t * 256 + n0 + i * 8] = v;
      }
    }
  }
}

// ---------------------------------------------------------------------------
// MFMA Gram (chunked): Mpart[ch][bh][e][dd] = sum_{l in 128-chunk} K[l][e]*V[l][dd].
// KT/VT are [c][l] -> both fragments contiguous us8 loads; LDS-free.
// All products/sums are integers (spikes 0/1) -> fp32-exact, order-free.
__global__ __launch_bounds__(256) void
k_kvM(const unsigned short* __restrict__ STkT,
      const unsigned short* __restrict__ STvT,
      float* __restrict__ Mpart) {
  int bh = blockIdx.x, ch = blockIdx.y;       // ch 0..7
  int b = bh >> 3, h = bh & 7;
  const unsigned short* KT = STkT + ((size_t)(b * NC + h * ND)) * NL;
  const unsigned short* VT = STvT + ((size_t)(b * NC + h * ND)) * NL;
  int tid = threadIdx.x;
  int w = tid >> 6, lane = tid & 63, quad = lane >> 4, l15 = lane & 15;
  int lb = ch * 128;

  f32x4 acc[4];
#pragma unroll
  for (int jj = 0; jj < 4; jj++) acc[jj] = (f32x4){0.f, 0.f, 0.f, 0.f};

#pragma unroll
  for (int ks = 0; ks < 4; ks++) {
    int lc = lb + ks * 32 + quad * 8;
    short8v a = *(const short8v*)&KT[(size_t)(w * 16 + l15) * NL + lc];
#pragma unroll
    for (int jj = 0; jj < 4; jj++) {
      short8v bv = *(const short8v*)&VT[(size_t)(jj * 16 + l15) * NL + lc];
      acc[jj] = __builtin_amdgcn_mfma_f32_16x16x32_bf16(a, bv, acc[jj], 0, 0, 0);
    }
  }

  float* Mp = Mpart + ((size_t)ch * 64 + bh) * 4096;
#pragma unroll
  for (int jj = 0; jj < 4; jj++)
#pragma unroll
    for (int r = 0; r < 4; r++)
      Mp[(w * 16 + quad * 4 + r) * ND + jj * 16 + l15] = acc[jj][r];
}

// ---------------------------------------------------------------------------
// k_red: one-time reduction of Mpart's 8 chunks -> Msum[bh][e][dd].
// Integer-valued floats -> exact, order-preserving vs old in-k_attn reduce.
__global__ __launch_bounds__(256) void
k_red(const float* __restrict__ Mpart, float* __restrict__ Msum) {
  int i = blockIdx.x * 256 + threadIdx.x;     // 65536 float4 slots
  float4 s = ((const float4*)Mpart)[i];
#pragma unroll
  for (int ch = 1; ch < 8; ch++) {
    float4 t = ((const float4*)Mpart)[(size_t)ch * 65536 + i];
    s.x += t.x; s.y += t.y; s.z += t.z; s.w += t.w;
  }
  ((float4*)Msum)[i] = s;
}

// ---------------------------------------------------------------------------
// MFMA attention: O^T[dd][l] = sum_e (M1+M2)^T[dd][e] * Q[l][e]; spike O>=12.
// M split into two exact bf16 planes (M integer <=1024 — split exact).
// Grid (8,64): 512 blocks, each 128 l-rows; prologue = one 16KB Msum read.
__global__ __launch_bounds__(256) void
k_attn(const unsigned short* __restrict__ STq,
       const float* __restrict__ Msum,
       unsigned short* __restrict__ STs) {
  __shared__ unsigned short MT1[64 * 64];   // [dd][e], 16B chunks phys = c ^ (dd&7)
  __shared__ unsigned short MT2[64 * 64];
  int lt = blockIdx.x, bh = blockIdx.y;     // lt 0..7
  int b = bh >> 3, h = bh & 7;
  int tid = threadIdx.x;
  int w = tid >> 6, lane = tid & 63, quad = lane >> 4, l15 = lane & 15;

#pragma unroll
  for (int i = 0; i < 4; i++) {
    int idx4 = tid + i * 256;
    float4 s = ((const float4*)Msum)[(size_t)bh * 1024 + idx4];
    int e = idx4 >> 4;
    int dd0 = (idx4 * 4) & 63;
    int chunk = e >> 3;
    float sv[4] = {s.x, s.y, s.z, s.w};
#pragma unroll
    for (int r = 0; r < 4; r++) {
      int dd = dd0 + r;
      unsigned short u1 = f2bu(sv[r]);
      unsigned short u2 = f2bu(sv[r] - bu2f(u1));
      int pos = dd * 64 + (((chunk ^ (dd & 7)) << 3) | (e & 7));
      MT1[pos] = u1;
      MT2[pos] = u2;
    }
  }
  __syncthreads();

  const unsigned short* Qp = STq + (size_t)b * NL * NC + h * ND;
  int lbase = lt * 128 + w * 32;

  f32x4 acc[4][2];                           // [ddtile][ltile]
#pragma unroll
  for (int dt = 0; dt < 4; dt++)
#pragma unroll
    for (int j = 0; j < 2; j++) acc[dt][j] = (f32x4){0.f, 0.f, 0.f, 0.f};

#pragma unroll
  for (int ks = 0; ks < 2; ks++) {
    short8v bq[2];
#pragma unroll
    for (int ltile = 0; ltile < 2; ltile++)
      bq[ltile] = *(const short8v*)&Qp[(size_t)(lbase + ltile * 16 + l15) * NC
                                       + ks * 32 + quad * 8];
    int c8 = ks * 4 + quad;
#pragma unroll
    for (int dt = 0; dt < 4; dt++) {
      int dd = dt * 16 + l15;
      int off = dd * 64 + ((c8 ^ (dd & 7)) << 3);
      short8v a1 = *(const short8v*)&MT1[off];
      short8v a2 = *(const short8v*)&MT2[off];
#pragma unroll
      for (int ltile = 0; ltile < 2; ltile++) {
        acc[dt][ltile] = __builtin_amdgcn_mfma_f32_16x16x32_bf16(a1, bq[ltile], acc[dt][ltile], 0, 0, 0);
        acc[dt][ltile] = __builtin_amdgcn_mfma_f32_16x16x32_bf16(a2, bq[ltile], acc[dt][ltile], 0, 0, 0);
      }
    }
  }

  unsigned short* Sp = STs + (size_t)b * NL * NC + h * ND;
#pragma unroll
  for (int dt = 0; dt < 4; dt++)
#pragma unroll
    for (int ltile = 0; ltile < 2; ltile++) {
      int l = lbase + ltile * 16 + l15;
      int dd = dt * 16 + quad * 4;
      us4 pk;
#pragma unroll
      for (int r = 0; r < 4; r++) pk[r] = (acc[dt][ltile][r] >= 12.0f) ? 0x3F80 : 0;
      *(us4*)&Sp[(size_t)l * NC + dd] = pk;
    }
}

// ---------------------------------------------------------------------------
// Final projection: 16x16x32, 128 rows x 64 cols; XCD-grouped swizzle +
// A-register double-buffer (round-11/15 version).
__global__ __launch_bounds__(256) void
k_out(const unsigned short* __restrict__ H2,
      const unsigned short* __restrict__ STs,
      const float* __restrict__ bp, float* __restrict__ out) {
  __shared__ __align__(16) unsigned short sB[2][64 * 64];

  int id = blockIdx.x;                  // 512 = 8 xcd * 64 slot
  int xcd = id & 7, slot = id >> 3;
  int qq = xcd * 64 + slot;             // ordered by (rt, b, l0)
  int rt = qq >> 7;
  int mi = qq & 127;
  int b  = mi >> 4;
  int l0 = (mi & 15) * 64;

  int tid = threadIdx.x;
  int w = tid >> 6, lane = tid & 63, quad = lane >> 4, l15 = lane & 15;
  int xorv = l15 & 7;

  const unsigned short* Sb = STs + (size_t)b * NL * NC;
  const unsigned short* Hbase = H2 + ((size_t)(9 * 4 + rt) * 8) * 8192;  // p=3

  f32x4 acc[2][4];
#pragma unroll
  for (int ri = 0; ri < 2; ri++)
#pragma unroll
    for (int jj = 0; jj < 4; jj++) acc[ri][jj] = (f32x4){0.f, 0.f, 0.f, 0.f};

  short8v A0[2][3][2], A1[2][3][2];

#define OLOADA(DST, K0I)                                                     \
  _Pragma("unroll") for (int ks = 0; ks < 2; ks++) {                         \
    int c8 = ks * 4 + quad;                                                  \
    _Pragma("unroll") for (int j = 0; j < 3; j++) {                          \
      const unsigned short* Hj =                                             \
          Hbase + ((size_t)(j * 4 * 8 + (K0I))) * 8192 + (size_t)c8 * 1024;  \
      DST[ks][j][0] = *(const short8v*)&Hj[(w * 32 + l15) * 8];              \
      DST[ks][j][1] = *(const short8v*)&Hj[(w * 32 + 16 + l15) * 8];         \
    }                                                                        \
  }

  OLOADA(A0, 0);

  us8 breg[2];
  int ccs[2], segs[2];
  size_t bsrc[2];
#pragma unroll
  for (int i = 0; i < 2; i++) {
    int idx = tid + i * 256;
    int cc = idx >> 3, seg = idx & 7;
    ccs[i] = cc; segs[i] = seg;
    bsrc[i] = (size_t)(l0 + cc) * NC + seg * 8;
  }
#pragma unroll
  for (int i = 0; i < 2; i++) breg[i] = *(const us8*)&Sb[bsrc[i]];
#pragma unroll
  for (int i = 0; i < 2; i++)
    *(us8*)&sB[0][ccs[i] * 64 + ((segs[i] ^ (ccs[i] & 7)) << 3)] = breg[i];

#define OBPRE(K0N)                                                           \
  _Pragma("unroll") for (int i = 0; i < 2; i++)                              \
    breg[i] = *(const us8*)&Sb[bsrc[i] + (size_t)(K0N) * 64];

#define OBWRITE(BUFN)                                                        \
  _Pragma("unroll") for (int i = 0; i < 2; i++)                              \
    *(us8*)&sB[BUFN][ccs[i] * 64 + ((segs[i] ^ (ccs[i] & 7)) << 3)] = breg[i];

#define OMFMAS(AR, BUF)                                                      \
  _Pragma("unroll") for (int ks = 0; ks < 2; ks++) {                         \
    int c8 = ks * 4 + quad;                                                  \
    int poff = (c8 ^ xorv) << 3;                                             \
    short8v bf[4];                                                           \
    _Pragma("unroll") for (int jj = 0; jj < 4; jj++)                         \
      bf[jj] = *(const short8v*)&sB[BUF][(jj * 16 + l15) * 64 + poff];       \
    _Pragma("unroll") for (int j = 0; j < 3; j++)                            \
      _Pragma("unroll") for (int jj = 0; jj < 4; jj++) {                     \
        acc[0][jj] = __builtin_amdgcn_mfma_f32_16x16x32_bf16(                \
            AR[ks][j][0], bf[jj], acc[0][jj], 0, 0, 0);                      \
        acc[1][jj] = __builtin_amdgcn_mfma_f32_16x16x32_bf16(                \
            AR[ks][j][1], bf[jj], acc[1][jj], 0, 0, 0);                      \
      }                                                                      \
  }

#define OSTEP(K0I, ACUR, ANXT)                                               \
  __syncthreads();                                                           \
  { if ((K0I) < 7) { OLOADA(ANXT, (K0I) + 1); } }                            \
  { if ((K0I) < 7) { OBPRE((K0I) + 1); } }                                   \
  OMFMAS(ACUR, (K0I) & 1);                                                   \
  { if ((K0I) < 7) { OBWRITE(((K0I) & 1) ^ 1); } }

  OSTEP(0, A0, A1)
  OSTEP(1, A1, A0)
  OSTEP(2, A0, A1)
  OSTEP(3, A1, A0)
  OSTEP(4, A0, A1)
  OSTEP(5, A1, A0)
  OSTEP(6, A0, A1)
  OSTEP(7, A1, A0)

#undef OLOADA
#undef OBPRE
#undef OBWRITE
#undef OMFMAS
#undef OSTEP

#pragma unroll
  for (int ri = 0; ri < 2; ri++) {
    int ob = rt * 128 + w * 32 + ri * 16 + quad * 4;
#pragma unroll
    for (int jj = 0; jj < 4; jj++) {
      int l = l0 + jj * 16 + l15;
#pragma unroll
      for (int r = 0; r < 4; r++)
        out[((size_t)(b * NC + ob + r)) * NL + l] = acc[ri][jj][r] + bp[ob + r];
    }
  }
}

// ---------------------------------------------------------------------------
extern "C" void kernel_launch(void* const* d_in, const int* in_sizes, int n_in,
                              void* d_out, int out_size, void* d_ws, size_t ws_size,
                              hipStream_t stream) {
  (void)in_sizes; (void)n_in; (void)out_size; (void)ws_size;
  const float* x   = (const float*)d_in[0];
  const float* wq  = (const float*)d_in[1];
  const float* wk  = (const float*)d_in[2];
  const float* wv  = (const float*)d_in[3];
  const float* wp  = (const float*)d_in[4];
  const float* bp  = (const float*)d_in[5];
  const float* gq  = (const float*)d_in[6];
  const float* bq  = (const float*)d_in[7];
  const float* mq  = (const float*)d_in[8];
  const float* vq  = (const float*)d_in[9];
  const float* gk  = (const float*)d_in[10];
  const float* bk  = (const float*)d_in[11];
  const float* mk  = (const float*)d_in[12];
  const float* vk  = (const float*)d_in[13];
  const float* gv  = (const float*)d_in[14];
  const float* bv  = (const float*)d_in[15];
  const float* mv  = (const float*)d_in[16];
  const float* vvv = (const float*)d_in[17];
  const float* gp  = (const float*)d_in[18];
  const float* bpn = (const float*)d_in[19];
  const float* mp  = (const float*)d_in[20];
  const float* vp  = (const float*)d_in[21];

  unsigned short* H2   = (unsigned short*)d_ws;
  unsigned short* ST0  = H2 + (size_t)4 * 3 * NC * NC;
  unsigned short* STq  = ST0 + BCL;
  unsigned short* STkT = STq + BCL;
  unsigned short* STvT = STkT + BCL;
  unsigned short* STs  = STvT + BCL;
  float* Mpart = (float*)(STs + BCL);   // 8 * 64 * 4096 floats
  float* Msum  = Mpart + (size_t)8 * 64 * 4096;  // 64 * 4096 floats

  dim3 blk(256);
  k_prep<<<1024, blk, 0, stream>>>(wq, wk, wv, wp, x, gp, bpn, mp, vp, H2, ST0);
  k_qkv<<<768, blk, 0, stream>>>(H2, ST0,
      gq, bq, mq, vq, gk, bk, mk, vk, gv, bv, mv, vvv, STq, STkT, STvT);
  k_kvM<<<dim3(64, 8), blk, 0, stream>>>(STkT, STvT, Mpart);
  k_red<<<256, blk, 0, stream>>>(Mpart, Msum);
  k_attn<<<dim3(8, 64), blk, 0, stream>>>(STq, Msum, STs);
  k_out<<<512, blk, 0, stream>>>(H2, STs, bp, (float*)d_out);
}

// Round 10
// 181.655 us; speedup vs baseline: 1.0946x; 1.0336x over previous
//
#include <hip/hip_runtime.h>
#include <hip/hip_bf16.h>

// SpikingSelfAttention — round 20: r19 base + batch-major XCD work lists.
// Old order (p,rt,b,n0) put all 8 batches' ST0 slices (8MB) concurrently on
// each XCD's 4MB L2 -> thrash (53MB FETCH vs 13MB cold). New order: b = xcd
// (96 blocks/batch for k_qkv, 64 for k_out) -> ST0[b]/STs[b] (1MB) become
// XCD-L2-resident; weight strips stream with 8-way co-resident reuse.
// Pure block->tile reassignment: numerics bit-identical.

#define NB 8
#define NC 512
#define NT 4
#define NN 256
#define NL 1024
#define NH 8
#define ND 64
#define BCL (NB*NC*NL)

typedef __attribute__((ext_vector_type(8))) short  short8v;
typedef __attribute__((ext_vector_type(8))) unsigned short us8;
typedef __attribute__((ext_vector_type(4))) unsigned short us4;
typedef __attribute__((ext_vector_type(4))) float f32x4;

__device__ __forceinline__ float bu2f(unsigned short u) {
  return __uint_as_float(((unsigned)u) << 16);
}
__device__ __forceinline__ unsigned short f2bu(float f) {   // RNE f32->bf16
  unsigned b = __float_as_uint(f);
  return (unsigned short)((b + 0x7FFFu + ((b >> 16) & 1u)) >> 16);
}

// ---------------------------------------------------------------------------
// k_prep: blocks [0,512) = weight split into fragment-ordered H2;
//         blocks [512,1024) = proj BN+LIF -> ST0[b][l][c] bf16.
// H2 layout: offset = ((((p*3+j)*4+rt)*8+k0i)*8+chunk)*1024 + r*8
__global__ void k_prep(const float* __restrict__ wq, const float* __restrict__ wk,
                       const float* __restrict__ wv, const float* __restrict__ wp,
                       const float* __restrict__ x,
                       const float* __restrict__ g,  const float* __restrict__ bt,
                       const float* __restrict__ mu, const float* __restrict__ var,
                       unsigned short* __restrict__ H2,
                       unsigned short* __restrict__ ST0) {
  if (blockIdx.x < 512) {
    int gi = blockIdx.x * 256 + threadIdx.x;       // (p,o,k8): 4*512*64
    int p = gi >> 15;
    int o = (gi >> 6) & 511;
    int k8 = gi & 63;
    int rt = o >> 7, r = o & 127;
    int k0i = k8 >> 3, chunk = k8 & 7;
    const float* W = (p == 0) ? wq : (p == 1) ? wk : (p == 2) ? wv : wp;
    const float* src = W + (size_t)o * NC + k8 * 8;
    us8 a[3];
#pragma unroll
    for (int i = 0; i < 8; i++) {
      float w = src[i];
      unsigned short u1 = f2bu(w);
      float r1 = w - bu2f(u1);
      unsigned short u2 = f2bu(r1);
      float r2 = r1 - bu2f(u2);
      unsigned short u3 = f2bu(r2);
      a[0][i] = u1; a[1][i] = u2; a[2][i] = u3;
    }
#pragma unroll
    for (int j = 0; j < 3; j++) {
      size_t off = ((size_t)((((p * 3 + j) * 4 + rt) * 8 + k0i) * 8 + chunk)) * 1024
                   + (size_t)r * 8;
      *(us8*)&H2[off] = a[j];
    }
  } else {
    int bidx = blockIdx.x - 512;
    int b  = bidx >> 6;
    int c0 = (bidx & 63) * 8;
    int n  = threadIdx.x;
    unsigned short spk[NT][8];
#pragma unroll
    for (int i = 0; i < 8; i++) {
      int c = c0 + i;
      float inv = g[c] / sqrtf(var[c] + 1e-5f);
      float m = mu[c], be = bt[c];
      const float* xp = x + ((size_t)(b * NC + c)) * NL + n;
      float v = 0.f;
#pragma unroll
      for (int t = 0; t < NT; t++) {
        float y = (xp[t * NN] - m) * inv + be;
        v = v + (y - v) / 1.5f;
        unsigned short s = 0;
        if (v - 1.0f >= 0.f) { s = 0x3F80; v = 0.f; }
        spk[t][i] = s;
      }
    }
#pragma unroll
    for (int t = 0; t < NT; t++) {
      us8 pk;
#pragma unroll
      for (int i = 0; i < 8; i++) pk[i] = spk[t][i];
      *(us8*)&ST0[((size_t)b * NL + t * NN + n) * NC + c0] = pk;
    }
  }
}

// ---------------------------------------------------------------------------
// Fused q/k/v projection + BN + LIF. 16x16x32 MFMA, 128x128 tile, 4x1 wave
// strips. Batch-major XCD mapping (b = xcd) + A-register double-buffer.
// Epilogue: q written [l][c]; k,v TRANSPOSED [c][l] via LDS 64B drains.
__global__ __launch_bounds__(256) void
k_qkv(const unsigned short* __restrict__ H2,
      const unsigned short* __restrict__ ST0,
      const float* __restrict__ gq, const float* __restrict__ bq,
      const float* __restrict__ mq, const float* __restrict__ vq,
      const float* __restrict__ gk, const float* __restrict__ bk,
      const float* __restrict__ mk, const float* __restrict__ vk,
      const float* __restrict__ gv, const float* __restrict__ bv,
      const float* __restrict__ mv, const float* __restrict__ vv,
      unsigned short* __restrict__ STq, unsigned short* __restrict__ STkT,
      unsigned short* __restrict__ STvT) {
  __shared__ __align__(16) unsigned short sB[2][128 * 64];

  int id = blockIdx.x;                  // 768 = 8 xcd * 96 slot
  int xcd = id & 7, slot = id >> 3;
  int b = xcd;                          // XCD-exclusive batch: ST0[b] L2-fits
  int grp = slot >> 3;                  // p*4+rt in [0,12)
  int p = grp >> 2, rt = grp & 3;
  int n0 = (slot & 7) * 32;

  int tid = threadIdx.x;
  int w = tid >> 6, lane = tid & 63, quad = lane >> 4, l15 = lane & 15;
  int xorv = l15 & 7;

  const unsigned short* Sb = ST0 + (size_t)b * NL * NC;
  const unsigned short* Hbase = H2 + ((size_t)((p * 3) * 4 + rt) * 8) * 8192;

  f32x4 acc[2][8];
#pragma unroll
  for (int ri = 0; ri < 2; ri++)
#pragma unroll
    for (int jj = 0; jj < 8; jj++) acc[ri][jj] = (f32x4){0.f, 0.f, 0.f, 0.f};

  // A-fragment double-buffer register sets (named, compile-time indexed).
  short8v A0[2][3][2], A1[2][3][2];

#define QLOADA(DST, K0I)                                                     \
  _Pragma("unroll") for (int ks = 0; ks < 2; ks++) {                         \
    int c8 = ks * 4 + quad;                                                  \
    _Pragma("unroll") for (int j = 0; j < 3; j++) {                          \
      const unsigned short* Hj =                                             \
          Hbase + ((size_t)(j * 4 * 8 + (K0I))) * 8192 + (size_t)c8 * 1024;  \
      DST[ks][j][0] = *(const short8v*)&Hj[(w * 32 + l15) * 8];              \
      DST[ks][j][1] = *(const short8v*)&Hj[(w * 32 + 16 + l15) * 8];         \
    }                                                                        \
  }

  QLOADA(A0, 0);                        // prologue A; latency hides under B-stage

  us8 breg[4];
  int ccs[4], segs[4];
  size_t bsrc[4];
#pragma unroll
  for (int i = 0; i < 4; i++) {
    int idx = tid + i * 256;
    int cc = idx >> 3, seg = idx & 7;
    int t = (cc >> 4) & 3, nn = (cc & 15) | ((cc >> 6) << 4);
    ccs[i] = cc; segs[i] = seg;
    bsrc[i] = (size_t)(t * NN + n0 + nn) * NC + seg * 8;
  }
#pragma unroll
  for (int i = 0; i < 4; i++) breg[i] = *(const us8*)&Sb[bsrc[i]];      // k0=0
#pragma unroll
  for (int i = 0; i < 4; i++)
    *(us8*)&sB[0][ccs[i] * 64 + ((segs[i] ^ (ccs[i] & 7)) << 3)] = breg[i];

#define QBPRE(K0N)                                                           \
  _Pragma("unroll") for (int i = 0; i < 4; i++)                              \
    breg[i] = *(const us8*)&Sb[bsrc[i] + (size_t)(K0N) * 64];

#define QBWRITE(BUFN)                                                        \
  _Pragma("unroll") for (int i = 0; i < 4; i++)                              \
    *(us8*)&sB[BUFN][ccs[i] * 64 + ((segs[i] ^ (ccs[i] & 7)) << 3)] = breg[i];

#define QMFMAS(AR, BUF)                                                      \
  _Pragma("unroll") for (int ks = 0; ks < 2; ks++) {                         \
    int c8 = ks * 4 + quad;                                                  \
    int poff = (c8 ^ xorv) << 3;                                             \
    short8v bf[8];                                                           \
    _Pragma("unroll") for (int jj = 0; jj < 8; jj++)                         \
      bf[jj] = *(const short8v*)&sB[BUF][(jj * 16 + l15) * 64 + poff];       \
    _Pragma("unroll") for (int j = 0; j < 3; j++)                            \
      _Pragma("unroll") for (int jj = 0; jj < 8; jj++) {                     \
        acc[0][jj] = __builtin_amdgcn_mfma_f32_16x16x32_bf16(                \
            AR[ks][j][0], bf[jj], acc[0][jj], 0, 0, 0);                      \
        acc[1][jj] = __builtin_amdgcn_mfma_f32_16x16x32_bf16(                \
            AR[ks][j][1], bf[jj], acc[1][jj], 0, 0, 0);                      \
      }                                                                      \
  }

#define QSTEP(K0I, ACUR, ANXT)                                               \
  __syncthreads();                                                           \
  { if ((K0I) < 7) { QLOADA(ANXT, (K0I) + 1); } }                            \
  { if ((K0I) < 7) { QBPRE((K0I) + 1); } }                                   \
  QMFMAS(ACUR, (K0I) & 1);                                                   \
  { if ((K0I) < 7) { QBWRITE(((K0I) & 1) ^ 1); } }

  QSTEP(0, A0, A1)
  QSTEP(1, A1, A0)
  QSTEP(2, A0, A1)
  QSTEP(3, A1, A0)
  QSTEP(4, A0, A1)
  QSTEP(5, A1, A0)
  QSTEP(6, A0, A1)
  QSTEP(7, A1, A0)

#undef QLOADA
#undef QBPRE
#undef QBWRITE
#undef QMFMAS
#undef QSTEP

  const float *g, *bb, *mpt, *vr;
  unsigned short* So;
  if (p == 0)      { g = gq; bb = bq; mpt = mq; vr = vq; So = STq; }
  else if (p == 1) { g = gk; bb = bk; mpt = mk; vr = vk; So = STkT; }
  else             { g = gv; bb = bv; mpt = mv; vr = vv; So = STvT; }
  So += (size_t)b * NL * NC;

  // Compute all spikes into registers first.
  unsigned short spa[2][2][4][4];       // [ri][nh][t][r]
#pragma unroll
  for (int ri = 0; ri < 2; ri++) {
    int ob = rt * 128 + w * 32 + ri * 16 + quad * 4;
    float av[4], mvv[4], bvv[4];
#pragma unroll
    for (int r = 0; r < 4; r++) {
      av[r]  = g[ob + r] / sqrtf(vr[ob + r] + 1e-5f);
      mvv[r] = mpt[ob + r];
      bvv[r] = bb[ob + r];
    }
#pragma unroll
    for (int nh = 0; nh < 2; nh++) {
#pragma unroll
      for (int r = 0; r < 4; r++) {
        float vmem = 0.f;
#pragma unroll
        for (int t = 0; t < NT; t++) {
          float y = (acc[ri][nh * 4 + t][r] - mvv[r]) * av[r] + bvv[r];
          vmem = vmem + (y - vmem) / 1.5f;
          unsigned short s = 0;
          if (vmem - 1.0f >= 0.f) { s = 0x3F80; vmem = 0.f; }
          spa[ri][nh][t][r] = s;
        }
      }
    }
  }

  __syncthreads();                      // K-loop sB reads done; safe to reuse

  if (p == 0) {
#pragma unroll
    for (int ri = 0; ri < 2; ri++) {
      int ob = rt * 128 + w * 32 + ri * 16 + quad * 4;
#pragma unroll
      for (int nh = 0; nh < 2; nh++) {
        int n = n0 + (nh << 4) + l15;
#pragma unroll
        for (int t = 0; t < NT; t++) {
          us4 pk;
#pragma unroll
          for (int r = 0; r < 4; r++) pk[r] = spa[ri][nh][t][r];
          *(us4*)&So[(size_t)(t * NN + n) * NC + ob] = pk;
        }
      }
    }
  } else {
    // Stage [c 128][l-packed 128] tile in LDS (XOR-swizzled 16B granules),
    // then drain 64B full-line segments: seg (c,t) -> So[c][t*256+n0 .. +32].
    unsigned short* sT = &sB[0][0];     // 32 KB, exactly sB
#pragma unroll
    for (int ri = 0; ri < 2; ri++)
#pragma unroll
      for (int nh = 0; nh < 2; nh++)
#pragma unroll
        for (int t = 0; t < 4; t++)
#pragma unroll
          for (int r = 0; r < 4; r++) {
            int row = w * 32 + ri * 16 + quad * 4 + r;
            int col = t * 32 + (nh << 4) + l15;
            int phys = (((col >> 3) ^ (row & 7)) << 3) | (col & 7);
            sT[row * 128 + phys] = spa[ri][nh][t][r];
          }
    __syncthreads();
#pragma unroll
    for (int ss = 0; ss < 2; ss++) {
      int s = tid + ss * 256;           // 512 segs = 128 c x 4 t
      int c = s >> 2, t = s & 3;
#pragma unroll
      for (int i = 0; i < 4; i++) {
        int g8 = t * 4 + i;
        us8 v = *(const us8*)&sT[c * 128 + ((g8 ^ (c & 7)) << 3)];
        *(us8*)&So[(size_t)(rt * 128 + c) * NL + t * 256 + n0 + i * 8] = v;
      }
    }
  }
}

// ---------------------------------------------------------------------------
// MFMA Gram (chunked): Mpart[ch][bh][e][dd] = sum_{l in 128-chunk} K[l][e]*V[l][dd].
// KT/VT are [c][l] -> both fragments contiguous us8 loads; LDS-free.
// All products/sums are integers (spikes 0/1) -> fp32-exact, order-free.
__global__ __launch_bounds__(256) void
k_kvM(const unsigned short* __restrict__ STkT,
      const unsigned short* __restrict__ STvT,
      float* __restrict__ Mpart) {
  int bh = blockIdx.x, ch = blockIdx.y;       // ch 0..7
  int b = bh >> 3, h = bh & 7;
  const unsigned short* KT = STkT + ((size_t)(b * NC + h * ND)) * NL;
  const unsigned short* VT = STvT + ((size_t)(b * NC + h * ND)) * NL;
  int tid = threadIdx.x;
  int w = tid >> 6, lane = tid & 63, quad = lane >> 4, l15 = lane & 15;
  int lb = ch * 128;

  f32x4 acc[4];
#pragma unroll
  for (int jj = 0; jj < 4; jj++) acc[jj] = (f32x4){0.f, 0.f, 0.f, 0.f};

#pragma unroll
  for (int ks = 0; ks < 4; ks++) {
    int lc = lb + ks * 32 + quad * 8;
    short8v a = *(const short8v*)&KT[(size_t)(w * 16 + l15) * NL + lc];
#pragma unroll
    for (int jj = 0; jj < 4; jj++) {
      short8v bv = *(const short8v*)&VT[(size_t)(jj * 16 + l15) * NL + lc];
      acc[jj] = __builtin_amdgcn_mfma_f32_16x16x32_bf16(a, bv, acc[jj], 0, 0, 0);
    }
  }

  float* Mp = Mpart + ((size_t)ch * 64 + bh) * 4096;
#pragma unroll
  for (int jj = 0; jj < 4; jj++)
#pragma unroll
    for (int r = 0; r < 4; r++)
      Mp[(w * 16 + quad * 4 + r) * ND + jj * 16 + l15] = acc[jj][r];
}

// ---------------------------------------------------------------------------
// k_red: one-time reduction of Mpart's 8 chunks -> Msum[bh][e][dd].
// Integer-valued floats -> exact, order-preserving vs old in-k_attn reduce.
__global__ __launch_bounds__(256) void
k_red(const float* __restrict__ Mpart, float* __restrict__ Msum) {
  int i = blockIdx.x * 256 + threadIdx.x;     // 65536 float4 slots
  float4 s = ((const float4*)Mpart)[i];
#pragma unroll
  for (int ch = 1; ch < 8; ch++) {
    float4 t = ((const float4*)Mpart)[(size_t)ch * 65536 + i];
    s.x += t.x; s.y += t.y; s.z += t.z; s.w += t.w;
  }
  ((float4*)Msum)[i] = s;
}

// ---------------------------------------------------------------------------
// MFMA attention: O^T[dd][l] = sum_e (M1+M2)^T[dd][e] * Q[l][e]; spike O>=12.
// M split into two exact bf16 planes (M integer <=1024 — split exact).
// Grid (8,64): 512 blocks, each 128 l-rows; prologue = one 16KB Msum read.
__global__ __launch_bounds__(256) void
k_attn(const unsigned short* __restrict__ STq,
       const float* __restrict__ Msum,
       unsigned short* __restrict__ STs) {
  __shared__ unsigned short MT1[64 * 64];   // [dd][e], 16B chunks phys = c ^ (dd&7)
  __shared__ unsigned short MT2[64 * 64];
  int lt = blockIdx.x, bh = blockIdx.y;     // lt 0..7
  int b = bh >> 3, h = bh & 7;
  int tid = threadIdx.x;
  int w = tid >> 6, lane = tid & 63, quad = lane >> 4, l15 = lane & 15;

#pragma unroll
  for (int i = 0; i < 4; i++) {
    int idx4 = tid + i * 256;
    float4 s = ((const float4*)Msum)[(size_t)bh * 1024 + idx4];
    int e = idx4 >> 4;
    int dd0 = (idx4 * 4) & 63;
    int chunk = e >> 3;
    float sv[4] = {s.x, s.y, s.z, s.w};
#pragma unroll
    for (int r = 0; r < 4; r++) {
      int dd = dd0 + r;
      unsigned short u1 = f2bu(sv[r]);
      unsigned short u2 = f2bu(sv[r] - bu2f(u1));
      int pos = dd * 64 + (((chunk ^ (dd & 7)) << 3) | (e & 7));
      MT1[pos] = u1;
      MT2[pos] = u2;
    }
  }
  __syncthreads();

  const unsigned short* Qp = STq + (size_t)b * NL * NC + h * ND;
  int lbase = lt * 128 + w * 32;

  f32x4 acc[4][2];                           // [ddtile][ltile]
#pragma unroll
  for (int dt = 0; dt < 4; dt++)
#pragma unroll
    for (int j = 0; j < 2; j++) acc[dt][j] = (f32x4){0.f, 0.f, 0.f, 0.f};

#pragma unroll
  for (int ks = 0; ks < 2; ks++) {
    short8v bq[2];
#pragma unroll
    for (int ltile = 0; ltile < 2; ltile++)
      bq[ltile] = *(const short8v*)&Qp[(size_t)(lbase + ltile * 16 + l15) * NC
                                       + ks * 32 + quad * 8];
    int c8 = ks * 4 + quad;
#pragma unroll
    for (int dt = 0; dt < 4; dt++) {
      int dd = dt * 16 + l15;
      int off = dd * 64 + ((c8 ^ (dd & 7)) << 3);
      short8v a1 = *(const short8v*)&MT1[off];
      short8v a2 = *(const short8v*)&MT2[off];
#pragma unroll
      for (int ltile = 0; ltile < 2; ltile++) {
        acc[dt][ltile] = __builtin_amdgcn_mfma_f32_16x16x32_bf16(a1, bq[ltile], acc[dt][ltile], 0, 0, 0);
        acc[dt][ltile] = __builtin_amdgcn_mfma_f32_16x16x32_bf16(a2, bq[ltile], acc[dt][ltile], 0, 0, 0);
      }
    }
  }

  unsigned short* Sp = STs + (size_t)b * NL * NC + h * ND;
#pragma unroll
  for (int dt = 0; dt < 4; dt++)
#pragma unroll
    for (int ltile = 0; ltile < 2; ltile++) {
      int l = lbase + ltile * 16 + l15;
      int dd = dt * 16 + quad * 4;
      us4 pk;
#pragma unroll
      for (int r = 0; r < 4; r++) pk[r] = (acc[dt][ltile][r] >= 12.0f) ? 0x3F80 : 0;
      *(us4*)&Sp[(size_t)l * NC + dd] = pk;
    }
}

// ---------------------------------------------------------------------------
// Final projection: 16x16x32, 128 rows x 64 cols; batch-major XCD mapping
// (b = xcd) + A-register double-buffer.
__global__ __launch_bounds__(256) void
k_out(const unsigned short* __restrict__ H2,
      const unsigned short* __restrict__ STs,
      const float* __restrict__ bp, float* __restrict__ out) {
  __shared__ __align__(16) unsigned short sB[2][64 * 64];

  int id = blockIdx.x;                  // 512 = 8 xcd * 64 slot
  int xcd = id & 7, slot = id >> 3;
  int b  = xcd;                         // XCD-exclusive batch: STs[b] L2-fits
  int rt = slot >> 4;
  int l0 = (slot & 15) * 64;

  int tid = threadIdx.x;
  int w = tid >> 6, lane = tid & 63, quad = lane >> 4, l15 = lane & 15;
  int xorv = l15 & 7;

  const unsigned short* Sb = STs + (size_t)b * NL * NC;
  const unsigned short* Hbase = H2 + ((size_t)(9 * 4 + rt) * 8) * 8192;  // p=3

  f32x4 acc[2][4];
#pragma unroll
  for (int ri = 0; ri < 2; ri++)
#pragma unroll
    for (int jj = 0; jj < 4; jj++) acc[ri][jj] = (f32x4){0.f, 0.f, 0.f, 0.f};

  short8v A0[2][3][2], A1[2][3][2];

#define OLOADA(DST, K0I)                                                     \
  _Pragma("unroll") for (int ks = 0; ks < 2; ks++) {                         \
    int c8 = ks * 4 + quad;                                                  \
    _Pragma("unroll") for (int j = 0; j < 3; j++) {                          \
      const unsigned short* Hj =                                             \
          Hbase + ((size_t)(j * 4 * 8 + (K0I))) * 8192 + (size_t)c8 * 1024;  \
      DST[ks][j][0] = *(const short8v*)&Hj[(w * 32 + l15) * 8];              \
      DST[ks][j][1] = *(const short8v*)&Hj[(w * 32 + 16 + l15) * 8];         \
    }                                                                        \
  }

  OLOADA(A0, 0);

  us8 breg[2];
  int ccs[2], segs[2];
  size_t bsrc[2];
#pragma unroll
  for (int i = 0; i < 2; i++) {
    int idx = tid + i * 256;
    int cc = idx >> 3, seg = idx & 7;
    ccs[i] = cc; segs[i] = seg;
    bsrc[i] = (size_t)(l0 + cc) * NC + seg * 8;
  }
#pragma unroll
  for (int i = 0; i < 2; i++) breg[i] = *(const us8*)&Sb[bsrc[i]];
#pragma unroll
  for (int i = 0; i < 2; i++)
    *(us8*)&sB[0][ccs[i] * 64 + ((segs[i] ^ (ccs[i] & 7)) << 3)] = breg[i];

#define OBPRE(K0N)                                                           \
  _Pragma("unroll") for (int i = 0; i < 2; i++)                              \
    breg[i] = *(const us8*)&Sb[bsrc[i] + (size_t)(K0N) * 64];

#define OBWRITE(BUFN)                                                        \
  _Pragma("unroll") for (int i = 0; i < 2; i++)                              \
    *(us8*)&sB[BUFN][ccs[i] * 64 + ((segs[i] ^ (ccs[i] & 7)) << 3)] = breg[i];

#define OMFMAS(AR, BUF)                                                      \
  _Pragma("unroll") for (int ks = 0; ks < 2; ks++) {                         \
    int c8 = ks * 4 + quad;                                                  \
    int poff = (c8 ^ xorv) << 3;                                             \
    short8v bf[4];                                                           \
    _Pragma("unroll") for (int jj = 0; jj < 4; jj++)                         \
      bf[jj] = *(const short8v*)&sB[BUF][(jj * 16 + l15) * 64 + poff];       \
    _Pragma("unroll") for (int j = 0; j < 3; j++)                            \
      _Pragma("unroll") for (int jj = 0; jj < 4; jj++) {                     \
        acc[0][jj] = __builtin_amdgcn_mfma_f32_16x16x32_bf16(                \
            AR[ks][j][0], bf[jj], acc[0][jj], 0, 0, 0);                      \
        acc[1][jj] = __builtin_amdgcn_mfma_f32_16x16x32_bf16(                \
            AR[ks][j][1], bf[jj], acc[1][jj], 0, 0, 0);                      \
      }                                                                      \
  }

#define OSTEP(K0I, ACUR, ANXT)                                               \
  __syncthreads();                                                           \
  { if ((K0I) < 7) { OLOADA(ANXT, (K0I) + 1); } }                            \
  { if ((K0I) < 7) { OBPRE((K0I) + 1); } }                                   \
  OMFMAS(ACUR, (K0I) & 1);                                                   \
  { if ((K0I) < 7) { OBWRITE(((K0I) & 1) ^ 1); } }

  OSTEP(0, A0, A1)
  OSTEP(1, A1, A0)
  OSTEP(2, A0, A1)
  OSTEP(3, A1, A0)
  OSTEP(4, A0, A1)
  OSTEP(5, A1, A0)
  OSTEP(6, A0, A1)
  OSTEP(7, A1, A0)

#undef OLOADA
#undef OBPRE
#undef OBWRITE
#undef OMFMAS
#undef OSTEP

#pragma unroll
  for (int ri = 0; ri < 2; ri++) {
    int ob = rt * 128 + w * 32 + ri * 16 + quad * 4;
#pragma unroll
    for (int jj = 0; jj < 4; jj++) {
      int l = l0 + jj * 16 + l15;
#pragma unroll
      for (int r = 0; r < 4; r++)
        out[((size_t)(b * NC + ob + r)) * NL + l] = acc[ri][jj][r] + bp[ob + r];
    }
  }
}

// ---------------------------------------------------------------------------
extern "C" void kernel_launch(void* const* d_in, const int* in_sizes, int n_in,
                              void* d_out, int out_size, void* d_ws, size_t ws_size,
                              hipStream_t stream) {
  (void)in_sizes; (void)n_in; (void)out_size; (void)ws_size;
  const float* x   = (const float*)d_in[0];
  const float* wq  = (const float*)d_in[1];
  const float* wk  = (const float*)d_in[2];
  const float* wv  = (const float*)d_in[3];
  const float* wp  = (const float*)d_in[4];
  const float* bp  = (const float*)d_in[5];
  const float* gq  = (const float*)d_in[6];
  const float* bq  = (const float*)d_in[7];
  const float* mq  = (const float*)d_in[8];
  const float* vq  = (const float*)d_in[9];
  const float* gk  = (const float*)d_in[10];
  const float* bk  = (const float*)d_in[11];
  const float* mk  = (const float*)d_in[12];
  const float* vk  = (const float*)d_in[13];
  const float* gv  = (const float*)d_in[14];
  const float* bv  = (const float*)d_in[15];
  const float* mv  = (const float*)d_in[16];
  const float* vvv = (const float*)d_in[17];
  const float* gp  = (const float*)d_in[18];
  const float* bpn = (const float*)d_in[19];
  const float* mp  = (const float*)d_in[20];
  const float* vp  = (const float*)d_in[21];

  unsigned short* H2   = (unsigned short*)d_ws;
  unsigned short* ST0  = H2 + (size_t)4 * 3 * NC * NC;
  unsigned short* STq  = ST0 + BCL;
  unsigned short* STkT = STq + BCL;
  unsigned short* STvT = STkT + BCL;
  unsigned short* STs  = STvT + BCL;
  float* Mpart = (float*)(STs + BCL);   // 8 * 64 * 4096 floats
  float* Msum  = Mpart + (size_t)8 * 64 * 4096;  // 64 * 4096 floats

  dim3 blk(256);
  k_prep<<<1024, blk, 0, stream>>>(wq, wk, wv, wp, x, gp, bpn, mp, vp, H2, ST0);
  k_qkv<<<768, blk, 0, stream>>>(H2, ST0,
      gq, bq, mq, vq, gk, bk, mk, vk, gv, bv, mv, vvv, STq, STkT, STvT);
  k_kvM<<<dim3(64, 8), blk, 0, stream>>>(STkT, STvT, Mpart);
  k_red<<<256, blk, 0, stream>>>(Mpart, Msum);
  k_attn<<<dim3(8, 64), blk, 0, stream>>>(STq, Msum, STs);
  k_out<<<512, blk, 0, stream>>>(H2, STs, bp, (float*)d_out);
}